// Round 5
// baseline (242.466 us; speedup 1.0000x reference)
//
#include <hip/hip_runtime.h>
#include <hip/hip_bf16.h>
#include <math.h>

// Problem constants
#define B_  8
#define T_  2048
#define C_  768
#define HS_ 256

// Split-K flash: q-block = 128 rows (16 per batch), k-tile = 64 keys,
// chunk = 4 k-tiles (256 keys). q-block qb has 2qb+2 k-tiles,
// chunks(qb) = qb/2+1; per-batch chunk total = 72; blocks = 8*72 = 576.
#define CHUNK_TILES 4
#define CHUNKS_PER_BATCH 72
#define NPART (CHUNKS_PER_BATCH * B_)   // 576

typedef float  f32x4  __attribute__((ext_vector_type(4)));
typedef __bf16 bf16x8 __attribute__((ext_vector_type(8)));
typedef __bf16 bf16x4 __attribute__((ext_vector_type(4)));

#define MFMA16(a, b, c) __builtin_amdgcn_mfma_f32_16x16x32_bf16((a), (b), (c), 0, 0, 0)

// global->LDS async copy, 16B per lane (dest = wave-uniform base + lane*16)
#define GLOAD_LDS16(gp, lp)                                                     \
    __builtin_amdgcn_global_load_lds(                                           \
        (const __attribute__((address_space(1))) void*)(gp),                    \
        (__attribute__((address_space(3))) void*)(lp), 16, 0, 0)

// cumulative chunk count before q-block qb: p=qb/2 -> p(p+1) + (qb&1)(p+1)
__device__ __forceinline__ int chunk_cum128(int qb) {
    int p = qb >> 1;
    return p * (p + 1) + (qb & 1) * (p + 1);
}

// ---------------------------------------------------------------------------
// Kernel 0: x fp32 -> bf16 (coalesced, 8 elem/thread)
// ---------------------------------------------------------------------------
__global__ __launch_bounds__(256) void xb_kernel(const float* __restrict__ x,
                                                 __bf16* __restrict__ xb) {
    size_t i = ((size_t)blockIdx.x * 256 + threadIdx.x) * 8;
    f32x4 a = *(const f32x4*)(x + i);
    f32x4 b = *(const f32x4*)(x + i + 4);
    bf16x8 o;
    o[0] = (__bf16)a[0]; o[1] = (__bf16)a[1]; o[2] = (__bf16)a[2]; o[3] = (__bf16)a[3];
    o[4] = (__bf16)b[0]; o[5] = (__bf16)b[1]; o[6] = (__bf16)b[2]; o[7] = (__bf16)b[3];
    *(bf16x8*)(xb + i) = o;
}

// ---------------------------------------------------------------------------
// Kernel 1: weights -> bf16, transposed to [n(768)][k(768)] (Q|K|V stacked).
// Softmax scale * log2(e) folded into Wq.
// ---------------------------------------------------------------------------
__global__ __launch_bounds__(256) void wt_kernel(const float* __restrict__ Wq,
                                                 const float* __restrict__ Wk,
                                                 const float* __restrict__ Wv,
                                                 __bf16* __restrict__ wt_all,
                                                 float qscale) {
    int idx = blockIdx.x * 256 + threadIdx.x;   // [0, 768*256)
    int mat = blockIdx.y;
    const float* W = (mat == 0) ? Wq : ((mat == 1) ? Wk : Wv);
    float scale = (mat == 0) ? qscale : 1.0f;
    int k = idx >> 8;    // 0..767
    int n = idx & 255;   // 0..255
    wt_all[((size_t)mat * HS_ + n) * C_ + k] = (__bf16)(W[idx] * scale);
}

// ---------------------------------------------------------------------------
// Kernel 2: fused QKV GEMM (m97 structure) -> fragment-layout q/k/v.
// Fragment layouts (element index, all *8 = 8 bf16 per lane slot):
//   Q: ((((b*32+qt)*4 + w16)*8 + ks )*64 + lane)
//   K: ((((b*32+kt)*8 + ks )*4 + ns )*64 + lane)
//   V: ((((b*32+kt)*2 + ks2)*16 + ntv)*64 + lane)
// ---------------------------------------------------------------------------
__global__ __launch_bounds__(256) void proj_kernel(const __bf16* __restrict__ xb,
                                                   const __bf16* __restrict__ wt,
                                                   __bf16* __restrict__ qf_,
                                                   __bf16* __restrict__ kf_,
                                                   __bf16* __restrict__ vf_) {
    __shared__ alignas(16) __bf16 ldsA[128 * 32];
    __shared__ alignas(16) __bf16 ldsB[128 * 32];

    const int tid  = threadIdx.x;
    const int w    = tid >> 6;
    const int lane = tid & 63;
    const int cm   = lane & 15;
    const int quad = lane >> 4;
    const int wm   = w & 1;
    const int wn   = w >> 1;
    const int m0   = blockIdx.x * 128;
    const int n0   = blockIdx.y * 128;

    f32x4 acc[4][4];
#pragma unroll
    for (int i = 0; i < 4; i++)
#pragma unroll
        for (int j = 0; j < 4; j++) acc[i][j] = (f32x4){0.f, 0.f, 0.f, 0.f};

    for (int k0 = 0; k0 < C_; k0 += 32) {
        __syncthreads();
#pragma unroll
        for (int h = 0; h < 2; h++) {
            int c = tid + h * 256;
            GLOAD_LDS16(xb + (size_t)(m0 + (c >> 2)) * C_ + k0 + (c & 3) * 8,
                        ldsA + c * 8);
        }
#pragma unroll
        for (int h = 0; h < 2; h++) {
            int c = tid + h * 256;
            GLOAD_LDS16(wt + (size_t)(n0 + (c >> 2)) * C_ + k0 + (c & 3) * 8,
                        ldsB + c * 8);
        }
        __syncthreads();

        bf16x8 af[4], bfr[4];
#pragma unroll
        for (int mt = 0; mt < 4; mt++)
            af[mt] = *(const bf16x8*)&ldsA[(wm * 64 + mt * 16 + cm) * 32 + quad * 8];
#pragma unroll
        for (int nt = 0; nt < 4; nt++)
            bfr[nt] = *(const bf16x8*)&ldsB[(wn * 64 + nt * 16 + cm) * 32 + quad * 8];
#pragma unroll
        for (int mt = 0; mt < 4; mt++)
#pragma unroll
            for (int nt = 0; nt < 4; nt++)
                acc[mt][nt] = MFMA16(af[mt], bfr[nt], acc[mt][nt]);
    }

    const int mat   = n0 >> 8;                 // 0=Q 1=K 2=V
    const int dBase = (n0 & 255) + wn * 64;
    const int b     = m0 >> 11;
    const int rt    = ((m0 & 2047) + wm * 64) >> 6;

    if (mat == 0) {
#pragma unroll
        for (int mt = 0; mt < 4; mt++)
#pragma unroll
            for (int nt = 0; nt < 4; nt++) {
                int ksq   = (dBase >> 5) + (nt >> 1);
                int quad2 = (nt & 1) * 2 + (cm >> 3);
                int j     = cm & 7;
                size_t base = ((((size_t)(b * 32 + rt) * 4 + mt) * 8 + ksq) * 64
                               + quad2 * 16) * 8 + j;
#pragma unroll
                for (int i = 0; i < 4; i++)
                    qf_[base + (quad * 4 + i) * 8] = (__bf16)acc[mt][nt][i];
            }
    } else if (mat == 1) {
#pragma unroll
        for (int mt = 0; mt < 4; mt++)
#pragma unroll
            for (int nt = 0; nt < 4; nt++) {
                int ksq   = (dBase >> 5) + (nt >> 1);
                int quad2 = (nt & 1) * 2 + (cm >> 3);
                int j     = cm & 7;
                size_t base = ((((size_t)(b * 32 + rt) * 8 + ksq) * 4 + mt) * 64
                               + quad2 * 16) * 8 + j;
#pragma unroll
                for (int i = 0; i < 4; i++)
                    kf_[base + (quad * 4 + i) * 8] = (__bf16)acc[mt][nt][i];
            }
    } else {
#pragma unroll
        for (int mt = 0; mt < 4; mt++) {
            int ks2   = (mt >> 1) & 1;
            int quadF = (mt & 1) * 2 + (quad >> 1);
            int jb    = (quad & 1) * 4;
#pragma unroll
            for (int nt = 0; nt < 4; nt++) {
                int ntv = (dBase >> 4) + nt;
                size_t idx = ((((size_t)(b * 32 + rt) * 2 + ks2) * 16 + ntv) * 64
                              + quadF * 16 + cm) * 8 + jb;
                bf16x4 v4;
                v4[0] = (__bf16)acc[mt][nt][0]; v4[1] = (__bf16)acc[mt][nt][1];
                v4[2] = (__bf16)acc[mt][nt][2]; v4[3] = (__bf16)acc[mt][nt][3];
                *(bf16x4*)(vf_ + idx) = v4;
            }
        }
    }
}

// ---------------------------------------------------------------------------
// Kernel 3a: split-K causal flash partial.
//   512 threads (8 waves), q-block = 128 rows (wave = 16 rows), one 64-key
//   K/V tile (64 KB) staged per iteration and shared by all 8 waves.
//   P aliases the consumed K region behind barrier (C).
//   Heavy chunks first; batch = pid&7 for L2/XCD locality.
//   Opart stored bf16 (unnormalized) + fp32 m/l per row.
// ---------------------------------------------------------------------------
__global__ __launch_bounds__(512, 4) void flash_part(const __bf16* __restrict__ qf_,
                                                     const __bf16* __restrict__ kf_,
                                                     const __bf16* __restrict__ vf_,
                                                     __bf16* __restrict__ Opart,
                                                     float* __restrict__ mpart,
                                                     float* __restrict__ lpart) {
    __shared__ alignas(16) __bf16 ldsK[8 * 4 * 64 * 8];   // 32 KB (P aliases head)
    __shared__ alignas(16) __bf16 ldsV[2 * 16 * 64 * 8];  // 32 KB

    const int tid  = threadIdx.x;
    const int w    = tid >> 6;       // 0..7
    const int lane = tid & 63;
    const int cm   = lane & 15;
    const int quad = lane >> 4;

    const int pid = blockIdx.x;                 // [0, 576)
    const int b   = pid & 7;                    // batch -> XCD locality
    const int r   = (CHUNKS_PER_BATCH - 1) - (pid >> 3);  // heavy chunks first
    int qb = 0, ci = 0;
    {
        int rr = r;
        for (int j = 0; j < 16; j++) {
            int c = (j >> 1) + 1;
            if (rr < c) { qb = j; ci = rr; break; }
            rr -= c;
        }
    }
    const int lpid = b * CHUNKS_PER_BATCH + r;  // logical output slot
    const int kt_begin = ci * CHUNK_TILES;
    const int kt_end   = min(kt_begin + CHUNK_TILES, 2 * qb + 2);

    // Q fragments: coalesced (base + lane*16B). Wave w covers q-rows
    // qb*128 + w*16 .. +15  -> 64-row q-tile qt = 2qb + (w>>2), sub w&3.
    const int qt = 2 * qb + (w >> 2);
    const __bf16* qp = qf_ + (((size_t)(b * 32 + qt) * 4 + (w & 3)) * 8) * 512 + lane * 8;
    bf16x8 qf[8];
#pragma unroll
    for (int ks = 0; ks < 8; ks++) qf[ks] = *(const bf16x8*)(qp + ks * 512);

    f32x4 accO[16];
#pragma unroll
    for (int i = 0; i < 16; i++) accO[i] = (f32x4){0.f, 0.f, 0.f, 0.f};
    float mi[4], li[4];
#pragma unroll
    for (int i = 0; i < 4; i++) { mi[i] = -__builtin_inff(); li[i] = 0.f; }

    const int wrow = qb * 128 + w * 16;          // wave's first q row (global)
    const int qg   = wrow + quad * 4;            // q row of acc reg i is qg+i

    for (int kt = kt_begin; kt < kt_end; kt++) {
        __syncthreads();   // (A) prior tile's LDS fully consumed by all waves

        // ---- stage K (32 KB) + V (32 KB) tile into LDS, async ----
        const __bf16* kg = kf_ + ((size_t)(b * 32 + kt) * 8) * 2048;
        const __bf16* vg = vf_ + ((size_t)(b * 32 + kt) * 2) * 8192;
#pragma unroll
        for (int h = 0; h < 4; h++) {
            GLOAD_LDS16(kg + (size_t)(h * 512 + tid) * 8, ldsK + (h * 512 + w * 64) * 8);
            GLOAD_LDS16(vg + (size_t)(h * 512 + tid) * 8, ldsV + (h * 512 + w * 64) * 8);
        }
        __syncthreads();   // (B) vmcnt drained -> K/V visible

        // ---- S = Q K^T (16 x 64 per wave) ----
        f32x4 s[4];
#pragma unroll
        for (int i = 0; i < 4; i++) s[i] = (f32x4){0.f, 0.f, 0.f, 0.f};
#pragma unroll
        for (int nsub = 0; nsub < 4; nsub++) {
#pragma unroll
            for (int ks = 0; ks < 8; ks++) {
                bf16x8 kfr = *(const bf16x8*)&ldsK[ks * 2048 + nsub * 512 + lane * 8];
                s[nsub] = MFMA16(qf[ks], kfr, s[nsub]);
            }
        }
        // ---- causal mask (only where tile can cross the diagonal) ----
        if (kt * 64 + 63 > wrow) {
#pragma unroll
            for (int nsub = 0; nsub < 4; nsub++)
#pragma unroll
                for (int i = 0; i < 4; i++)
                    if (kt * 64 + nsub * 16 + cm > qg + i)
                        s[nsub][i] = -__builtin_inff();
        }
        // ---- online softmax (rows in 16-lane quads) ----
        float pm[4];
#pragma unroll
        for (int i = 0; i < 4; i++)
            pm[i] = fmaxf(fmaxf(s[0][i], s[1][i]), fmaxf(s[2][i], s[3][i]));
#pragma unroll
        for (int off = 1; off < 16; off <<= 1)
#pragma unroll
            for (int i = 0; i < 4; i++)
                pm[i] = fmaxf(pm[i], __shfl_xor(pm[i], off));

        float alpha[4], rs[4], p[4][4];
#pragma unroll
        for (int i = 0; i < 4; i++) {
            float mn = fmaxf(mi[i], pm[i]);
            alpha[i] = exp2f(mi[i] - mn);
            mi[i] = mn;
            rs[i] = 0.f;
        }
#pragma unroll
        for (int nsub = 0; nsub < 4; nsub++)
#pragma unroll
            for (int i = 0; i < 4; i++) {
                p[nsub][i] = exp2f(s[nsub][i] - mi[i]);
                rs[i] += p[nsub][i];
            }
#pragma unroll
        for (int off = 1; off < 16; off <<= 1)
#pragma unroll
            for (int i = 0; i < 4; i++)
                rs[i] += __shfl_xor(rs[i], off);
#pragma unroll
        for (int i = 0; i < 4; i++) li[i] = li[i] * alpha[i] + rs[i];
#pragma unroll
        for (int nt = 0; nt < 16; nt++)
#pragma unroll
            for (int i = 0; i < 4; i++) accO[nt][i] *= alpha[i];

        __syncthreads();   // (C) all waves done reading ldsK -> safe to alias P

        // ---- P -> per-wave LDS slice (aliases ldsK), A-frag order ----
        __bf16* ldsP = ldsK + w * 1024;
#pragma unroll
        for (int nsub = 0; nsub < 4; nsub++)
#pragma unroll
            for (int i = 0; i < 4; i++) {
                int c = nsub * 16 + cm;
                ldsP[(c >> 5) * 512 + ((c >> 3) & 3) * 128 + (quad * 4 + i) * 8 + (c & 7)]
                    = (__bf16)p[nsub][i];
            }
        // ---- O += P V ----
#pragma unroll
        for (int ks2 = 0; ks2 < 2; ks2++) {
            bf16x8 pf = *(const bf16x8*)&ldsP[ks2 * 512 + quad * 128 + cm * 8];
#pragma unroll
            for (int nt = 0; nt < 16; nt++) {
                bf16x8 vfr = *(const bf16x8*)&ldsV[ks2 * 8192 + nt * 512 + lane * 8];
                accO[nt] = MFMA16(pf, vfr, accO[nt]);
            }
        }
    }

    // epilogue: unnormalized bf16 partial + fp32 (m, l)
    const int rloc = w * 16 + quad * 4;          // local row of acc reg i
    __bf16* op = Opart + ((size_t)lpid * 128 + rloc) * HS_;
#pragma unroll
    for (int nt = 0; nt < 16; nt++)
#pragma unroll
        for (int i = 0; i < 4; i++)
            op[(size_t)i * HS_ + nt * 16 + cm] = (__bf16)accO[nt][i];
    if (cm == 0) {
#pragma unroll
        for (int i = 0; i < 4; i++) {
            mpart[lpid * 128 + rloc + i] = mi[i];
            lpart[lpid * 128 + rloc + i] = li[i];
        }
    }
}

// ---------------------------------------------------------------------------
// Kernel 3b: combine partials.  Grid (128, 8): block = (b, qb) x 16 rows.
// ---------------------------------------------------------------------------
__global__ __launch_bounds__(256) void flash_combine(const __bf16* __restrict__ Opart,
                                                     const float* __restrict__ mpart,
                                                     const float* __restrict__ lpart,
                                                     float* __restrict__ out) {
    const int b    = blockIdx.x >> 4;
    const int qb   = blockIdx.x & 15;
    const int nc   = (qb >> 1) + 1;
    const int pid0 = b * CHUNKS_PER_BATCH + chunk_cum128(qb);

    const int tid  = threadIdx.x;
    const int col  = (tid & 63) * 4;
    const int r0   = blockIdx.y * 16 + (tid >> 6) * 4;

    for (int rr = 0; rr < 4; rr++) {
        const int row = r0 + rr;
        float ms = -__builtin_inff();
        for (int c = 0; c < nc; c++)
            ms = fmaxf(ms, mpart[(pid0 + c) * 128 + row]);
        f32x4 acc = (f32x4){0.f, 0.f, 0.f, 0.f};
        float l = 0.f;
        for (int c = 0; c < nc; c++) {
            float sc = exp2f(mpart[(pid0 + c) * 128 + row] - ms);
            l += lpart[(pid0 + c) * 128 + row] * sc;
            bf16x4 o = *(const bf16x4*)(Opart + ((size_t)(pid0 + c) * 128 + row) * HS_ + col);
            acc[0] += (float)o[0] * sc; acc[1] += (float)o[1] * sc;
            acc[2] += (float)o[2] * sc; acc[3] += (float)o[3] * sc;
        }
        float inv = 1.0f / l;
        f32x4 res = (f32x4){acc[0] * inv, acc[1] * inv, acc[2] * inv, acc[3] * inv};
        *(f32x4*)(out + ((size_t)(b * T_ + qb * 128 + row)) * HS_ + col) = res;
    }
}

// ---------------------------------------------------------------------------
extern "C" void kernel_launch(void* const* d_in, const int* in_sizes, int n_in,
                              void* d_out, int out_size, void* d_ws, size_t ws_size,
                              hipStream_t stream) {
    const float* x  = (const float*)d_in[0];
    const float* Wq = (const float*)d_in[1];
    const float* Wk = (const float*)d_in[2];
    const float* Wv = (const float*)d_in[3];
    float* out = (float*)d_out;

    char* ws = (char*)d_ws;
    // ws layout (bytes); xb unioned with Opart (xb dead after proj):
    //   wt_all : 768*768*2            = 1,179,648
    //   qfrag/kfrag/vfrag             = 3 x 8,388,608
    //   union  : xb 25,165,824 | Opart(bf16) 37,748,736 + mpart/lpart 294,912 x2
    size_t off = 0;
    __bf16* wt_all = (__bf16*)(ws + off); off += 1179648;
    __bf16* qfrag  = (__bf16*)(ws + off); off += 8388608;
    __bf16* kfrag  = (__bf16*)(ws + off); off += 8388608;
    __bf16* vfrag  = (__bf16*)(ws + off); off += 8388608;
    __bf16* xb     = (__bf16*)(ws + off);              // union with Opart
    __bf16* Opart  = (__bf16*)(ws + off); off += (size_t)NPART * 128 * HS_ * 2;
    float*  mpart  = (float*)(ws + off);  off += (size_t)NPART * 128 * 4;
    float*  lpart  = (float*)(ws + off);

    float qscale = 1.4426950408889634f / sqrtf((float)C_);

    xb_kernel<<<dim3(6144), 256, 0, stream>>>(x, xb);
    wt_kernel<<<dim3(768, 3), 256, 0, stream>>>(Wq, Wk, Wv, wt_all, qscale);
    proj_kernel<<<dim3(128, 6), 256, 0, stream>>>(xb, wt_all, qfrag, kfrag, vfrag);
    flash_part<<<dim3(NPART), 512, 0, stream>>>(qfrag, kfrag, vfrag, Opart, mpart, lpart);
    flash_combine<<<dim3(128, 8), 256, 0, stream>>>(Opart, mpart, lpart, out);
}

// Round 6
// 220.103 us; speedup vs baseline: 1.1016x; 1.1016x over previous
//
#include <hip/hip_runtime.h>
#include <hip/hip_bf16.h>
#include <math.h>

// Problem constants
#define B_  8
#define T_  2048
#define C_  768
#define HS_ 256

// Split-K flash: q-block = 128 rows, k-tile = 64 keys, chunk = 4 k-tiles.
// q-block qb has 2qb+2 k-tiles, chunks(qb) = qb/2+1; per-batch total = 72.
#define CHUNK_TILES 4
#define CHUNKS_PER_BATCH 72
#define NPART (CHUNKS_PER_BATCH * B_)   // 576

typedef float  f32x4  __attribute__((ext_vector_type(4)));
typedef __bf16 bf16x8 __attribute__((ext_vector_type(8)));
typedef __bf16 bf16x4 __attribute__((ext_vector_type(4)));

#define MFMA16(a, b, c) __builtin_amdgcn_mfma_f32_16x16x32_bf16((a), (b), (c), 0, 0, 0)

// global->LDS async copy, 16B per lane (dest = wave-uniform base + lane*16)
#define GLOAD_LDS16(gp, lp)                                                     \
    __builtin_amdgcn_global_load_lds(                                           \
        (const __attribute__((address_space(1))) void*)(gp),                    \
        (__attribute__((address_space(3))) void*)(lp), 16, 0, 0)

__device__ __forceinline__ int chunk_cum128(int qb) {
    int p = qb >> 1;
    return p * (p + 1) + (qb & 1) * (p + 1);
}

// ---------------------------------------------------------------------------
// Kernel 1: weights -> bf16, transposed to [n(768)][k(768)] (Q|K|V stacked).
// Softmax scale * log2(e) folded into Wq.
// ---------------------------------------------------------------------------
__global__ __launch_bounds__(256) void wt_kernel(const float* __restrict__ Wq,
                                                 const float* __restrict__ Wk,
                                                 const float* __restrict__ Wv,
                                                 __bf16* __restrict__ wt_all,
                                                 float qscale) {
    int idx = blockIdx.x * 256 + threadIdx.x;   // [0, 768*256)
    int mat = blockIdx.y;
    const float* W = (mat == 0) ? Wq : ((mat == 1) ? Wk : Wv);
    float scale = (mat == 0) ? qscale : 1.0f;
    int k = idx >> 8;    // 0..767
    int n = idx & 255;   // 0..255
    wt_all[((size_t)mat * HS_ + n) * C_ + k] = (__bf16)(W[idx] * scale);
}

// ---------------------------------------------------------------------------
// Kernel 2: fused QKV GEMM, reads x fp32 directly (no pre-cast kernel).
//   A-tile staged as fp32 via global_load_lds (16 KB), converted to bf16 at
//   fragment read. Grid (6 n-tiles, 128 m-tiles): the 6 blocks sharing an
//   m-tile are adjacent in dispatch for x reuse in L2/L3.
// Fragment layouts (element index, all *8 = 8 bf16 per lane slot):
//   Q: ((((b*32+qt)*4 + w16)*8 + ks )*64 + lane)
//   K: ((((b*32+kt)*8 + ks )*4 + ns )*64 + lane)
//   V: ((((b*32+kt)*2 + ks2)*16 + ntv)*64 + lane)
// ---------------------------------------------------------------------------
__global__ __launch_bounds__(256) void proj_kernel(const float* __restrict__ x,
                                                   const __bf16* __restrict__ wt,
                                                   __bf16* __restrict__ qf_,
                                                   __bf16* __restrict__ kf_,
                                                   __bf16* __restrict__ vf_) {
    __shared__ alignas(16) float  ldsA[128 * 32];   // 16 KB fp32 A-tile
    __shared__ alignas(16) __bf16 ldsB[128 * 32];   //  8 KB bf16 B-tile

    const int tid  = threadIdx.x;
    const int w    = tid >> 6;
    const int lane = tid & 63;
    const int cm   = lane & 15;
    const int quad = lane >> 4;
    const int wm   = w & 1;
    const int wn   = w >> 1;
    const int n0   = blockIdx.x * 128;
    const int m0   = blockIdx.y * 128;

    f32x4 acc[4][4];
#pragma unroll
    for (int i = 0; i < 4; i++)
#pragma unroll
        for (int j = 0; j < 4; j++) acc[i][j] = (f32x4){0.f, 0.f, 0.f, 0.f};

    for (int k0 = 0; k0 < C_; k0 += 32) {
        __syncthreads();
        // A: 1024 16B-chunks (4 fp32). chunk c: row = c>>3, col = (c&7)*4
#pragma unroll
        for (int h = 0; h < 4; h++) {
            int c = tid + h * 256;
            GLOAD_LDS16(x + (size_t)(m0 + (c >> 3)) * C_ + k0 + (c & 7) * 4,
                        ldsA + c * 4);
        }
        // B: 512 16B-chunks (8 bf16). chunk c: row = c>>2, col = (c&3)*8
#pragma unroll
        for (int h = 0; h < 2; h++) {
            int c = tid + h * 256;
            GLOAD_LDS16(wt + (size_t)(n0 + (c >> 2)) * C_ + k0 + (c & 3) * 8,
                        ldsB + c * 8);
        }
        __syncthreads();

        bf16x8 af[4], bfr[4];
#pragma unroll
        for (int mt = 0; mt < 4; mt++) {
            const float* ap = &ldsA[(wm * 64 + mt * 16 + cm) * 32 + quad * 8];
            f32x4 xa = *(const f32x4*)ap;
            f32x4 xb4 = *(const f32x4*)(ap + 4);
            af[mt][0] = (__bf16)xa[0]; af[mt][1] = (__bf16)xa[1];
            af[mt][2] = (__bf16)xa[2]; af[mt][3] = (__bf16)xa[3];
            af[mt][4] = (__bf16)xb4[0]; af[mt][5] = (__bf16)xb4[1];
            af[mt][6] = (__bf16)xb4[2]; af[mt][7] = (__bf16)xb4[3];
        }
#pragma unroll
        for (int nt = 0; nt < 4; nt++)
            bfr[nt] = *(const bf16x8*)&ldsB[(wn * 64 + nt * 16 + cm) * 32 + quad * 8];
#pragma unroll
        for (int mt = 0; mt < 4; mt++)
#pragma unroll
            for (int nt = 0; nt < 4; nt++)
                acc[mt][nt] = MFMA16(af[mt], bfr[nt], acc[mt][nt]);
    }

    const int mat   = n0 >> 8;                 // 0=Q 1=K 2=V
    const int dBase = (n0 & 255) + wn * 64;
    const int b     = m0 >> 11;
    const int rt    = ((m0 & 2047) + wm * 64) >> 6;

    if (mat == 0) {
#pragma unroll
        for (int mt = 0; mt < 4; mt++)
#pragma unroll
            for (int nt = 0; nt < 4; nt++) {
                int ksq   = (dBase >> 5) + (nt >> 1);
                int quad2 = (nt & 1) * 2 + (cm >> 3);
                int j     = cm & 7;
                size_t base = ((((size_t)(b * 32 + rt) * 4 + mt) * 8 + ksq) * 64
                               + quad2 * 16) * 8 + j;
#pragma unroll
                for (int i = 0; i < 4; i++)
                    qf_[base + (quad * 4 + i) * 8] = (__bf16)acc[mt][nt][i];
            }
    } else if (mat == 1) {
#pragma unroll
        for (int mt = 0; mt < 4; mt++)
#pragma unroll
            for (int nt = 0; nt < 4; nt++) {
                int ksq   = (dBase >> 5) + (nt >> 1);
                int quad2 = (nt & 1) * 2 + (cm >> 3);
                int j     = cm & 7;
                size_t base = ((((size_t)(b * 32 + rt) * 8 + ksq) * 4 + mt) * 64
                               + quad2 * 16) * 8 + j;
#pragma unroll
                for (int i = 0; i < 4; i++)
                    kf_[base + (quad * 4 + i) * 8] = (__bf16)acc[mt][nt][i];
            }
    } else {
#pragma unroll
        for (int mt = 0; mt < 4; mt++) {
            int ks2   = (mt >> 1) & 1;
            int quadF = (mt & 1) * 2 + (quad >> 1);
            int jb    = (quad & 1) * 4;
#pragma unroll
            for (int nt = 0; nt < 4; nt++) {
                int ntv = (dBase >> 4) + nt;
                size_t idx = ((((size_t)(b * 32 + rt) * 2 + ks2) * 16 + ntv) * 64
                              + quadF * 16 + cm) * 8 + jb;
                bf16x4 v4;
                v4[0] = (__bf16)acc[mt][nt][0]; v4[1] = (__bf16)acc[mt][nt][1];
                v4[2] = (__bf16)acc[mt][nt][2]; v4[3] = (__bf16)acc[mt][nt][3];
                *(bf16x4*)(vf_ + idx) = v4;
            }
        }
    }
}

// ---------------------------------------------------------------------------
// Kernel 3a: split-K causal flash partial.
//   512 threads (8 waves), q-block = 128 rows (wave = 16 rows), one 64-key
//   K/V tile (64 KB) staged per iteration and shared by all 8 waves.
//   NO min-wave launch bound: R5's (512,4) capped VGPR at 64 -> scratch
//   spills (FETCH 118 MB). Let the allocator have ~124+AGPR.
// ---------------------------------------------------------------------------
__global__ __launch_bounds__(512) void flash_part(const __bf16* __restrict__ qf_,
                                                  const __bf16* __restrict__ kf_,
                                                  const __bf16* __restrict__ vf_,
                                                  __bf16* __restrict__ Opart,
                                                  float* __restrict__ mpart,
                                                  float* __restrict__ lpart) {
    __shared__ alignas(16) __bf16 ldsK[8 * 4 * 64 * 8];   // 32 KB (P aliases head)
    __shared__ alignas(16) __bf16 ldsV[2 * 16 * 64 * 8];  // 32 KB

    const int tid  = threadIdx.x;
    const int w    = tid >> 6;       // 0..7
    const int lane = tid & 63;
    const int cm   = lane & 15;
    const int quad = lane >> 4;

    const int pid = blockIdx.x;                 // [0, 576)
    const int b   = pid & 7;                    // batch -> XCD locality
    const int r   = (CHUNKS_PER_BATCH - 1) - (pid >> 3);  // heavy chunks first
    int qb = 0, ci = 0;
    {
        int rr = r;
        for (int j = 0; j < 16; j++) {
            int c = (j >> 1) + 1;
            if (rr < c) { qb = j; ci = rr; break; }
            rr -= c;
        }
    }
    const int lpid = b * CHUNKS_PER_BATCH + r;  // logical output slot
    const int kt_begin = ci * CHUNK_TILES;
    const int kt_end   = min(kt_begin + CHUNK_TILES, 2 * qb + 2);

    // Q fragments: coalesced (base + lane*16B). Wave w covers q-rows
    // qb*128 + w*16 .. +15  -> 64-row q-tile qt = 2qb + (w>>2), sub w&3.
    const int qt = 2 * qb + (w >> 2);
    const __bf16* qp = qf_ + (((size_t)(b * 32 + qt) * 4 + (w & 3)) * 8) * 512 + lane * 8;
    bf16x8 qf[8];
#pragma unroll
    for (int ks = 0; ks < 8; ks++) qf[ks] = *(const bf16x8*)(qp + ks * 512);

    f32x4 accO[16];
#pragma unroll
    for (int i = 0; i < 16; i++) accO[i] = (f32x4){0.f, 0.f, 0.f, 0.f};
    float mi[4], li[4];
#pragma unroll
    for (int i = 0; i < 4; i++) { mi[i] = -__builtin_inff(); li[i] = 0.f; }

    const int wrow = qb * 128 + w * 16;          // wave's first q row (global)
    const int qg   = wrow + quad * 4;            // q row of acc reg i is qg+i

    for (int kt = kt_begin; kt < kt_end; kt++) {
        __syncthreads();   // (A) prior tile's LDS fully consumed by all waves

        // ---- stage K (32 KB) + V (32 KB) tile into LDS, async ----
        const __bf16* kg = kf_ + ((size_t)(b * 32 + kt) * 8) * 2048;
        const __bf16* vg = vf_ + ((size_t)(b * 32 + kt) * 2) * 8192;
#pragma unroll
        for (int h = 0; h < 4; h++) {
            GLOAD_LDS16(kg + (size_t)(h * 512 + tid) * 8, ldsK + (h * 512 + w * 64) * 8);
            GLOAD_LDS16(vg + (size_t)(h * 512 + tid) * 8, ldsV + (h * 512 + w * 64) * 8);
        }
        __syncthreads();   // (B) vmcnt drained -> K/V visible

        // ---- S = Q K^T (16 x 64 per wave) ----
        f32x4 s[4];
#pragma unroll
        for (int i = 0; i < 4; i++) s[i] = (f32x4){0.f, 0.f, 0.f, 0.f};
#pragma unroll
        for (int nsub = 0; nsub < 4; nsub++) {
#pragma unroll
            for (int ks = 0; ks < 8; ks++) {
                bf16x8 kfr = *(const bf16x8*)&ldsK[ks * 2048 + nsub * 512 + lane * 8];
                s[nsub] = MFMA16(qf[ks], kfr, s[nsub]);
            }
        }
        // ---- causal mask (only where tile can cross the diagonal) ----
        if (kt * 64 + 63 > wrow) {
#pragma unroll
            for (int nsub = 0; nsub < 4; nsub++)
#pragma unroll
                for (int i = 0; i < 4; i++)
                    if (kt * 64 + nsub * 16 + cm > qg + i)
                        s[nsub][i] = -__builtin_inff();
        }
        // ---- online softmax (rows in 16-lane quads) ----
        float pm[4];
#pragma unroll
        for (int i = 0; i < 4; i++)
            pm[i] = fmaxf(fmaxf(s[0][i], s[1][i]), fmaxf(s[2][i], s[3][i]));
#pragma unroll
        for (int off = 1; off < 16; off <<= 1)
#pragma unroll
            for (int i = 0; i < 4; i++)
                pm[i] = fmaxf(pm[i], __shfl_xor(pm[i], off));

        float alpha[4], rs[4], p[4][4];
#pragma unroll
        for (int i = 0; i < 4; i++) {
            float mn = fmaxf(mi[i], pm[i]);
            alpha[i] = exp2f(mi[i] - mn);
            mi[i] = mn;
            rs[i] = 0.f;
        }
#pragma unroll
        for (int nsub = 0; nsub < 4; nsub++)
#pragma unroll
            for (int i = 0; i < 4; i++) {
                p[nsub][i] = exp2f(s[nsub][i] - mi[i]);
                rs[i] += p[nsub][i];
            }
#pragma unroll
        for (int off = 1; off < 16; off <<= 1)
#pragma unroll
            for (int i = 0; i < 4; i++)
                rs[i] += __shfl_xor(rs[i], off);
#pragma unroll
        for (int i = 0; i < 4; i++) li[i] = li[i] * alpha[i] + rs[i];
#pragma unroll
        for (int nt = 0; nt < 16; nt++)
#pragma unroll
            for (int i = 0; i < 4; i++) accO[nt][i] *= alpha[i];

        __syncthreads();   // (C) all waves done reading ldsK -> safe to alias P

        // ---- P -> per-wave LDS slice (aliases ldsK), A-frag order ----
        __bf16* ldsP = ldsK + w * 1024;
#pragma unroll
        for (int nsub = 0; nsub < 4; nsub++)
#pragma unroll
            for (int i = 0; i < 4; i++) {
                int c = nsub * 16 + cm;
                ldsP[(c >> 5) * 512 + ((c >> 3) & 3) * 128 + (quad * 4 + i) * 8 + (c & 7)]
                    = (__bf16)p[nsub][i];
            }
        // ---- O += P V ----
#pragma unroll
        for (int ks2 = 0; ks2 < 2; ks2++) {
            bf16x8 pf = *(const bf16x8*)&ldsP[ks2 * 512 + quad * 128 + cm * 8];
#pragma unroll
            for (int nt = 0; nt < 16; nt++) {
                bf16x8 vfr = *(const bf16x8*)&ldsV[ks2 * 8192 + nt * 512 + lane * 8];
                accO[nt] = MFMA16(pf, vfr, accO[nt]);
            }
        }
    }

    // epilogue: unnormalized bf16 partial + fp32 (m, l)
    const int rloc = w * 16 + quad * 4;          // local row of acc reg i
    __bf16* op = Opart + ((size_t)lpid * 128 + rloc) * HS_;
#pragma unroll
    for (int nt = 0; nt < 16; nt++)
#pragma unroll
        for (int i = 0; i < 4; i++)
            op[(size_t)i * HS_ + nt * 16 + cm] = (__bf16)accO[nt][i];
    if (cm == 0) {
#pragma unroll
        for (int i = 0; i < 4; i++) {
            mpart[lpid * 128 + rloc + i] = mi[i];
            lpart[lpid * 128 + rloc + i] = li[i];
        }
    }
}

// ---------------------------------------------------------------------------
// Kernel 3b: combine partials.  Grid (128, 8): block = (b, qb) x 16 rows.
// ---------------------------------------------------------------------------
__global__ __launch_bounds__(256) void flash_combine(const __bf16* __restrict__ Opart,
                                                     const float* __restrict__ mpart,
                                                     const float* __restrict__ lpart,
                                                     float* __restrict__ out) {
    const int b    = blockIdx.x >> 4;
    const int qb   = blockIdx.x & 15;
    const int nc   = (qb >> 1) + 1;
    const int pid0 = b * CHUNKS_PER_BATCH + chunk_cum128(qb);

    const int tid  = threadIdx.x;
    const int col  = (tid & 63) * 4;
    const int r0   = blockIdx.y * 16 + (tid >> 6) * 4;

    for (int rr = 0; rr < 4; rr++) {
        const int row = r0 + rr;
        float ms = -__builtin_inff();
        for (int c = 0; c < nc; c++)
            ms = fmaxf(ms, mpart[(pid0 + c) * 128 + row]);
        f32x4 acc = (f32x4){0.f, 0.f, 0.f, 0.f};
        float l = 0.f;
        for (int c = 0; c < nc; c++) {
            float sc = exp2f(mpart[(pid0 + c) * 128 + row] - ms);
            l += lpart[(pid0 + c) * 128 + row] * sc;
            bf16x4 o = *(const bf16x4*)(Opart + ((size_t)(pid0 + c) * 128 + row) * HS_ + col);
            acc[0] += (float)o[0] * sc; acc[1] += (float)o[1] * sc;
            acc[2] += (float)o[2] * sc; acc[3] += (float)o[3] * sc;
        }
        float inv = 1.0f / l;
        f32x4 res = (f32x4){acc[0] * inv, acc[1] * inv, acc[2] * inv, acc[3] * inv};
        *(f32x4*)(out + ((size_t)(b * T_ + qb * 128 + row)) * HS_ + col) = res;
    }
}

// ---------------------------------------------------------------------------
extern "C" void kernel_launch(void* const* d_in, const int* in_sizes, int n_in,
                              void* d_out, int out_size, void* d_ws, size_t ws_size,
                              hipStream_t stream) {
    const float* x  = (const float*)d_in[0];
    const float* Wq = (const float*)d_in[1];
    const float* Wk = (const float*)d_in[2];
    const float* Wv = (const float*)d_in[3];
    float* out = (float*)d_out;

    char* ws = (char*)d_ws;
    // ws layout (bytes):
    //   wt_all : 768*768*2            = 1,179,648
    //   qfrag/kfrag/vfrag             = 3 x 8,388,608
    //   Opart(bf16) 37,748,736 + mpart/lpart 294,912 x2
    size_t off = 0;
    __bf16* wt_all = (__bf16*)(ws + off); off += 1179648;
    __bf16* qfrag  = (__bf16*)(ws + off); off += 8388608;
    __bf16* kfrag  = (__bf16*)(ws + off); off += 8388608;
    __bf16* vfrag  = (__bf16*)(ws + off); off += 8388608;
    __bf16* Opart  = (__bf16*)(ws + off); off += (size_t)NPART * 128 * HS_ * 2;
    float*  mpart  = (float*)(ws + off);  off += (size_t)NPART * 128 * 4;
    float*  lpart  = (float*)(ws + off);

    float qscale = 1.4426950408889634f / sqrtf((float)C_);

    wt_kernel<<<dim3(768, 3), 256, 0, stream>>>(Wq, Wk, Wv, wt_all, qscale);
    proj_kernel<<<dim3(6, 128), 256, 0, stream>>>(x, wt_all, qfrag, kfrag, vfrag);
    flash_part<<<dim3(NPART), 512, 0, stream>>>(qfrag, kfrag, vfrag, Opart, mpart, lpart);
    flash_combine<<<dim3(128, 8), 256, 0, stream>>>(Opart, mpart, lpart, out);
}

// Round 7
// 212.080 us; speedup vs baseline: 1.1433x; 1.0378x over previous
//
#include <hip/hip_runtime.h>
#include <hip/hip_bf16.h>
#include <math.h>

// Problem constants
#define B_  8
#define T_  2048
#define C_  768
#define HS_ 256

// Split-K flash: q-block = 128 rows, k-tile = 64 keys, chunk = 4 k-tiles.
// q-block qb has 2qb+2 k-tiles, chunks(qb) = qb/2+1; per-batch total = 72.
#define CHUNK_TILES 4
#define CHUNKS_PER_BATCH 72
#define NPART (CHUNKS_PER_BATCH * B_)   // 576

typedef float  f32x4  __attribute__((ext_vector_type(4)));
typedef __bf16 bf16x8 __attribute__((ext_vector_type(8)));
typedef __bf16 bf16x4 __attribute__((ext_vector_type(4)));

#define MFMA16(a, b, c) __builtin_amdgcn_mfma_f32_16x16x32_bf16((a), (b), (c), 0, 0, 0)

// global->LDS async copy, 16B per lane (dest = wave-uniform base + lane*16)
#define GLOAD_LDS16(gp, lp)                                                     \
    __builtin_amdgcn_global_load_lds(                                           \
        (const __attribute__((address_space(1))) void*)(gp),                    \
        (__attribute__((address_space(3))) void*)(lp), 16, 0, 0)

__device__ __forceinline__ int chunk_cum128(int qb) {
    int p = qb >> 1;
    return p * (p + 1) + (qb & 1) * (p + 1);
}

// ---------------------------------------------------------------------------
// Kernel 0: x fp32 -> bf16 (coalesced, 8 elem/thread)
// ---------------------------------------------------------------------------
__global__ __launch_bounds__(256) void xb_kernel(const float* __restrict__ x,
                                                 __bf16* __restrict__ xb) {
    size_t i = ((size_t)blockIdx.x * 256 + threadIdx.x) * 8;
    f32x4 a = *(const f32x4*)(x + i);
    f32x4 b = *(const f32x4*)(x + i + 4);
    bf16x8 o;
    o[0] = (__bf16)a[0]; o[1] = (__bf16)a[1]; o[2] = (__bf16)a[2]; o[3] = (__bf16)a[3];
    o[4] = (__bf16)b[0]; o[5] = (__bf16)b[1]; o[6] = (__bf16)b[2]; o[7] = (__bf16)b[3];
    *(bf16x8*)(xb + i) = o;
}

// ---------------------------------------------------------------------------
// Kernel 1: weights -> bf16, transposed to [n(768)][k(768)] (Q|K|V stacked).
// Softmax scale * log2(e) folded into Wq.
// ---------------------------------------------------------------------------
__global__ __launch_bounds__(256) void wt_kernel(const float* __restrict__ Wq,
                                                 const float* __restrict__ Wk,
                                                 const float* __restrict__ Wv,
                                                 __bf16* __restrict__ wt_all,
                                                 float qscale) {
    int idx = blockIdx.x * 256 + threadIdx.x;   // [0, 768*256)
    int mat = blockIdx.y;
    const float* W = (mat == 0) ? Wq : ((mat == 1) ? Wk : Wv);
    float scale = (mat == 0) ? qscale : 1.0f;
    int k = idx >> 8;    // 0..767
    int n = idx & 255;   // 0..255
    wt_all[((size_t)mat * HS_ + n) * C_ + k] = (__bf16)(W[idx] * scale);
}

// ---------------------------------------------------------------------------
// Kernel 2: fused QKV GEMM (bf16 in, BK=64 -> 12 k-iters, half the barriers).
// Fragment layouts (element index, all *8 = 8 bf16 per lane slot):
//   Q: ((((b*32+qt)*4 + w16)*8 + ks )*64 + lane)
//   K: ((((b*32+kt)*8 + ks )*4 + ns )*64 + lane)
//   V: ((((b*32+kt)*2 + ks2)*16 + ntv)*64 + lane)
// ---------------------------------------------------------------------------
__global__ __launch_bounds__(256) void proj_kernel(const __bf16* __restrict__ xb,
                                                   const __bf16* __restrict__ wt,
                                                   __bf16* __restrict__ qf_,
                                                   __bf16* __restrict__ kf_,
                                                   __bf16* __restrict__ vf_) {
    __shared__ alignas(16) __bf16 ldsA[128 * 64];   // 16 KB
    __shared__ alignas(16) __bf16 ldsB[128 * 64];   // 16 KB

    const int tid  = threadIdx.x;
    const int w    = tid >> 6;
    const int lane = tid & 63;
    const int cm   = lane & 15;
    const int quad = lane >> 4;
    const int wm   = w & 1;
    const int wn   = w >> 1;
    const int m0   = blockIdx.x * 128;
    const int n0   = blockIdx.y * 128;

    f32x4 acc[4][4];
#pragma unroll
    for (int i = 0; i < 4; i++)
#pragma unroll
        for (int j = 0; j < 4; j++) acc[i][j] = (f32x4){0.f, 0.f, 0.f, 0.f};

    for (int k0 = 0; k0 < C_; k0 += 64) {
        __syncthreads();
        // 1024 16B-chunks each: row = c>>3, col granule = (c&7)*8
#pragma unroll
        for (int h = 0; h < 4; h++) {
            int c = tid + h * 256;
            GLOAD_LDS16(xb + (size_t)(m0 + (c >> 3)) * C_ + k0 + (c & 7) * 8,
                        ldsA + c * 8);
        }
#pragma unroll
        for (int h = 0; h < 4; h++) {
            int c = tid + h * 256;
            GLOAD_LDS16(wt + (size_t)(n0 + (c >> 3)) * C_ + k0 + (c & 7) * 8,
                        ldsB + c * 8);
        }
        __syncthreads();

#pragma unroll
        for (int ks = 0; ks < 2; ks++) {
            bf16x8 af[4], bfr[4];
#pragma unroll
            for (int mt = 0; mt < 4; mt++)
                af[mt] = *(const bf16x8*)&ldsA[(wm * 64 + mt * 16 + cm) * 64 + ks * 32 + quad * 8];
#pragma unroll
            for (int nt = 0; nt < 4; nt++)
                bfr[nt] = *(const bf16x8*)&ldsB[(wn * 64 + nt * 16 + cm) * 64 + ks * 32 + quad * 8];
#pragma unroll
            for (int mt = 0; mt < 4; mt++)
#pragma unroll
                for (int nt = 0; nt < 4; nt++)
                    acc[mt][nt] = MFMA16(af[mt], bfr[nt], acc[mt][nt]);
        }
    }

    const int mat   = n0 >> 8;                 // 0=Q 1=K 2=V
    const int dBase = (n0 & 255) + wn * 64;
    const int b     = m0 >> 11;
    const int rt    = ((m0 & 2047) + wm * 64) >> 6;

    if (mat == 0) {
#pragma unroll
        for (int mt = 0; mt < 4; mt++)
#pragma unroll
            for (int nt = 0; nt < 4; nt++) {
                int ksq   = (dBase >> 5) + (nt >> 1);
                int quad2 = (nt & 1) * 2 + (cm >> 3);
                int j     = cm & 7;
                size_t base = ((((size_t)(b * 32 + rt) * 4 + mt) * 8 + ksq) * 64
                               + quad2 * 16) * 8 + j;
#pragma unroll
                for (int i = 0; i < 4; i++)
                    qf_[base + (quad * 4 + i) * 8] = (__bf16)acc[mt][nt][i];
            }
    } else if (mat == 1) {
#pragma unroll
        for (int mt = 0; mt < 4; mt++)
#pragma unroll
            for (int nt = 0; nt < 4; nt++) {
                int ksq   = (dBase >> 5) + (nt >> 1);
                int quad2 = (nt & 1) * 2 + (cm >> 3);
                int j     = cm & 7;
                size_t base = ((((size_t)(b * 32 + rt) * 8 + ksq) * 4 + mt) * 64
                               + quad2 * 16) * 8 + j;
#pragma unroll
                for (int i = 0; i < 4; i++)
                    kf_[base + (quad * 4 + i) * 8] = (__bf16)acc[mt][nt][i];
            }
    } else {
#pragma unroll
        for (int mt = 0; mt < 4; mt++) {
            int ks2   = (mt >> 1) & 1;
            int quadF = (mt & 1) * 2 + (quad >> 1);
            int jb    = (quad & 1) * 4;
#pragma unroll
            for (int nt = 0; nt < 4; nt++) {
                int ntv = (dBase >> 4) + nt;
                size_t idx = ((((size_t)(b * 32 + rt) * 2 + ks2) * 16 + ntv) * 64
                              + quadF * 16 + cm) * 8 + jb;
                bf16x4 v4;
                v4[0] = (__bf16)acc[mt][nt][0]; v4[1] = (__bf16)acc[mt][nt][1];
                v4[2] = (__bf16)acc[mt][nt][2]; v4[3] = (__bf16)acc[mt][nt][3];
                *(bf16x4*)(vf_ + idx) = v4;
            }
        }
    }
}

// ---------------------------------------------------------------------------
// Kernel 3a: split-K causal flash partial.
//   512 threads (8 waves). ONE barrier per k-tile:
//   - K/V double-buffered in LDS (2 x 64 KB); prefetch of tile kt+1 issues
//     right after the barrier and flies during the whole compute phase.
//   - P has a dedicated per-wave LDS region (no aliasing) -> no P barrier;
//     intra-wave ds ordering (lgkmcnt) is handled by the compiler.
//   VGPR (~148 incl AGPR) limits to 1 block/CU, so intra-block overlap is
//   the only latency hiding available -- this structure provides it.
// ---------------------------------------------------------------------------
__global__ __launch_bounds__(512) void flash_part(const __bf16* __restrict__ qf_,
                                                  const __bf16* __restrict__ kf_,
                                                  const __bf16* __restrict__ vf_,
                                                  __bf16* __restrict__ Opart,
                                                  float* __restrict__ mpart,
                                                  float* __restrict__ lpart) {
    __shared__ alignas(16) __bf16 ldsK[2][8 * 4 * 64 * 8];   // 2 x 32 KB
    __shared__ alignas(16) __bf16 ldsV[2][2 * 16 * 64 * 8];  // 2 x 32 KB
    __shared__ alignas(16) __bf16 ldsPw[8][1024];            // 8 KB (per-wave P)

    const int tid  = threadIdx.x;
    const int w    = tid >> 6;       // 0..7
    const int lane = tid & 63;
    const int cm   = lane & 15;
    const int quad = lane >> 4;

    const int pid = blockIdx.x;                 // [0, 576)
    const int b   = pid & 7;                    // batch -> XCD locality
    const int r   = (CHUNKS_PER_BATCH - 1) - (pid >> 3);  // heavy chunks first
    int qb = 0, ci = 0;
    {
        int rr = r;
        for (int j = 0; j < 16; j++) {
            int c = (j >> 1) + 1;
            if (rr < c) { qb = j; ci = rr; break; }
            rr -= c;
        }
    }
    const int lpid = b * CHUNKS_PER_BATCH + r;  // logical output slot
    const int kt_begin = ci * CHUNK_TILES;
    const int kt_end   = min(kt_begin + CHUNK_TILES, 2 * qb + 2);
    const int ntile    = kt_end - kt_begin;

    // Q fragments: coalesced (base + lane*16B). Wave w covers q-rows
    // qb*128 + w*16 .. +15  -> 64-row q-tile qt = 2qb + (w>>2), sub w&3.
    const int qt = 2 * qb + (w >> 2);
    const __bf16* qp = qf_ + (((size_t)(b * 32 + qt) * 4 + (w & 3)) * 8) * 512 + lane * 8;
    bf16x8 qf[8];
#pragma unroll
    for (int ks = 0; ks < 8; ks++) qf[ks] = *(const bf16x8*)(qp + ks * 512);

    f32x4 accO[16];
#pragma unroll
    for (int i = 0; i < 16; i++) accO[i] = (f32x4){0.f, 0.f, 0.f, 0.f};
    float mi[4], li[4];
#pragma unroll
    for (int i = 0; i < 4; i++) { mi[i] = -__builtin_inff(); li[i] = 0.f; }

    const int wrow = qb * 128 + w * 16;          // wave's first q row (global)
    const int qg   = wrow + quad * 4;            // q row of acc reg i is qg+i

    // ---- prologue: stage first tile into buffer 0 ----
    {
        const __bf16* kg = kf_ + ((size_t)(b * 32 + kt_begin) * 8) * 2048;
        const __bf16* vg = vf_ + ((size_t)(b * 32 + kt_begin) * 2) * 8192;
#pragma unroll
        for (int h = 0; h < 4; h++) {
            GLOAD_LDS16(kg + (size_t)(h * 512 + tid) * 8, ldsK[0] + (h * 512 + w * 64) * 8);
            GLOAD_LDS16(vg + (size_t)(h * 512 + tid) * 8, ldsV[0] + (h * 512 + w * 64) * 8);
        }
    }

    for (int it = 0; it < ntile; it++) {
        const int kt  = kt_begin + it;
        const int cur = it & 1;

        __syncthreads();   // drains vmcnt -> buf[cur] staged & visible;
                           // all waves are done reading buf[cur^1] (last iter)

        // ---- prefetch next tile into the other buffer (flies during compute)
        if (it + 1 < ntile) {
            const __bf16* kg = kf_ + ((size_t)(b * 32 + kt + 1) * 8) * 2048;
            const __bf16* vg = vf_ + ((size_t)(b * 32 + kt + 1) * 2) * 8192;
#pragma unroll
            for (int h = 0; h < 4; h++) {
                GLOAD_LDS16(kg + (size_t)(h * 512 + tid) * 8,
                            ldsK[cur ^ 1] + (h * 512 + w * 64) * 8);
                GLOAD_LDS16(vg + (size_t)(h * 512 + tid) * 8,
                            ldsV[cur ^ 1] + (h * 512 + w * 64) * 8);
            }
        }

        // ---- S = Q K^T (16 x 64 per wave) ----
        f32x4 s[4];
#pragma unroll
        for (int i = 0; i < 4; i++) s[i] = (f32x4){0.f, 0.f, 0.f, 0.f};
#pragma unroll
        for (int nsub = 0; nsub < 4; nsub++) {
#pragma unroll
            for (int ks = 0; ks < 8; ks++) {
                bf16x8 kfr = *(const bf16x8*)&ldsK[cur][ks * 2048 + nsub * 512 + lane * 8];
                s[nsub] = MFMA16(qf[ks], kfr, s[nsub]);
            }
        }
        // ---- causal mask (only where tile can cross the diagonal) ----
        if (kt * 64 + 63 > wrow) {
#pragma unroll
            for (int nsub = 0; nsub < 4; nsub++)
#pragma unroll
                for (int i = 0; i < 4; i++)
                    if (kt * 64 + nsub * 16 + cm > qg + i)
                        s[nsub][i] = -__builtin_inff();
        }
        // ---- online softmax (rows in 16-lane quads, wave-local) ----
        float pm[4];
#pragma unroll
        for (int i = 0; i < 4; i++)
            pm[i] = fmaxf(fmaxf(s[0][i], s[1][i]), fmaxf(s[2][i], s[3][i]));
#pragma unroll
        for (int off = 1; off < 16; off <<= 1)
#pragma unroll
            for (int i = 0; i < 4; i++)
                pm[i] = fmaxf(pm[i], __shfl_xor(pm[i], off));

        float alpha[4], rs[4], p[4][4];
#pragma unroll
        for (int i = 0; i < 4; i++) {
            float mn = fmaxf(mi[i], pm[i]);
            alpha[i] = exp2f(mi[i] - mn);
            mi[i] = mn;
            rs[i] = 0.f;
        }
#pragma unroll
        for (int nsub = 0; nsub < 4; nsub++)
#pragma unroll
            for (int i = 0; i < 4; i++) {
                p[nsub][i] = exp2f(s[nsub][i] - mi[i]);
                rs[i] += p[nsub][i];
            }
#pragma unroll
        for (int off = 1; off < 16; off <<= 1)
#pragma unroll
            for (int i = 0; i < 4; i++)
                rs[i] += __shfl_xor(rs[i], off);
#pragma unroll
        for (int i = 0; i < 4; i++) li[i] = li[i] * alpha[i] + rs[i];
#pragma unroll
        for (int nt = 0; nt < 16; nt++)
#pragma unroll
            for (int i = 0; i < 4; i++) accO[nt][i] *= alpha[i];

        // ---- P -> own per-wave LDS slice (private; no barrier needed) ----
        __bf16* ldsP = ldsPw[w];
#pragma unroll
        for (int nsub = 0; nsub < 4; nsub++)
#pragma unroll
            for (int i = 0; i < 4; i++) {
                int c = nsub * 16 + cm;
                ldsP[(c >> 5) * 512 + ((c >> 3) & 3) * 128 + (quad * 4 + i) * 8 + (c & 7)]
                    = (__bf16)p[nsub][i];
            }
        // ---- O += P V ----
#pragma unroll
        for (int ks2 = 0; ks2 < 2; ks2++) {
            bf16x8 pf = *(const bf16x8*)&ldsP[ks2 * 512 + quad * 128 + cm * 8];
#pragma unroll
            for (int nt = 0; nt < 16; nt++) {
                bf16x8 vfr = *(const bf16x8*)&ldsV[cur][ks2 * 8192 + nt * 512 + lane * 8];
                accO[nt] = MFMA16(pf, vfr, accO[nt]);
            }
        }
    }

    // epilogue: unnormalized bf16 partial + fp32 (m, l)
    const int rloc = w * 16 + quad * 4;          // local row of acc reg i
    __bf16* op = Opart + ((size_t)lpid * 128 + rloc) * HS_;
#pragma unroll
    for (int nt = 0; nt < 16; nt++)
#pragma unroll
        for (int i = 0; i < 4; i++)
            op[(size_t)i * HS_ + nt * 16 + cm] = (__bf16)accO[nt][i];
    if (cm == 0) {
#pragma unroll
        for (int i = 0; i < 4; i++) {
            mpart[lpid * 128 + rloc + i] = mi[i];
            lpart[lpid * 128 + rloc + i] = li[i];
        }
    }
}

// ---------------------------------------------------------------------------
// Kernel 3b: combine partials.  Grid (128, 8): block = (b, qb) x 16 rows.
// ---------------------------------------------------------------------------
__global__ __launch_bounds__(256) void flash_combine(const __bf16* __restrict__ Opart,
                                                     const float* __restrict__ mpart,
                                                     const float* __restrict__ lpart,
                                                     float* __restrict__ out) {
    const int b    = blockIdx.x >> 4;
    const int qb   = blockIdx.x & 15;
    const int nc   = (qb >> 1) + 1;
    const int pid0 = b * CHUNKS_PER_BATCH + chunk_cum128(qb);

    const int tid  = threadIdx.x;
    const int col  = (tid & 63) * 4;
    const int r0   = blockIdx.y * 16 + (tid >> 6) * 4;

    for (int rr = 0; rr < 4; rr++) {
        const int row = r0 + rr;
        float ms = -__builtin_inff();
        for (int c = 0; c < nc; c++)
            ms = fmaxf(ms, mpart[(pid0 + c) * 128 + row]);
        f32x4 acc = (f32x4){0.f, 0.f, 0.f, 0.f};
        float l = 0.f;
        for (int c = 0; c < nc; c++) {
            float sc = exp2f(mpart[(pid0 + c) * 128 + row] - ms);
            l += lpart[(pid0 + c) * 128 + row] * sc;
            bf16x4 o = *(const bf16x4*)(Opart + ((size_t)(pid0 + c) * 128 + row) * HS_ + col);
            acc[0] += (float)o[0] * sc; acc[1] += (float)o[1] * sc;
            acc[2] += (float)o[2] * sc; acc[3] += (float)o[3] * sc;
        }
        float inv = 1.0f / l;
        f32x4 res = (f32x4){acc[0] * inv, acc[1] * inv, acc[2] * inv, acc[3] * inv};
        *(f32x4*)(out + ((size_t)(b * T_ + qb * 128 + row)) * HS_ + col) = res;
    }
}

// ---------------------------------------------------------------------------
extern "C" void kernel_launch(void* const* d_in, const int* in_sizes, int n_in,
                              void* d_out, int out_size, void* d_ws, size_t ws_size,
                              hipStream_t stream) {
    const float* x  = (const float*)d_in[0];
    const float* Wq = (const float*)d_in[1];
    const float* Wk = (const float*)d_in[2];
    const float* Wv = (const float*)d_in[3];
    float* out = (float*)d_out;

    char* ws = (char*)d_ws;
    // ws layout (bytes); xb unioned with Opart (xb dead after proj):
    //   wt_all : 768*768*2            = 1,179,648
    //   qfrag/kfrag/vfrag             = 3 x 8,388,608
    //   union  : xb 25,165,824 | Opart(bf16) 37,748,736; then mpart/lpart
    size_t off = 0;
    __bf16* wt_all = (__bf16*)(ws + off); off += 1179648;
    __bf16* qfrag  = (__bf16*)(ws + off); off += 8388608;
    __bf16* kfrag  = (__bf16*)(ws + off); off += 8388608;
    __bf16* vfrag  = (__bf16*)(ws + off); off += 8388608;
    __bf16* xb     = (__bf16*)(ws + off);              // union with Opart
    __bf16* Opart  = (__bf16*)(ws + off); off += (size_t)NPART * 128 * HS_ * 2;
    float*  mpart  = (float*)(ws + off);  off += (size_t)NPART * 128 * 4;
    float*  lpart  = (float*)(ws + off);

    float qscale = 1.4426950408889634f / sqrtf((float)C_);

    xb_kernel<<<dim3(6144), 256, 0, stream>>>(x, xb);
    wt_kernel<<<dim3(768, 3), 256, 0, stream>>>(Wq, Wk, Wv, wt_all, qscale);
    proj_kernel<<<dim3(128, 6), 256, 0, stream>>>(xb, wt_all, qfrag, kfrag, vfrag);
    flash_part<<<dim3(NPART), 512, 0, stream>>>(qfrag, kfrag, vfrag, Opart, mpart, lpart);
    flash_combine<<<dim3(128, 8), 256, 0, stream>>>(Opart, mpart, lpart, out);
}

// Round 8
// 202.082 us; speedup vs baseline: 1.1998x; 1.0495x over previous
//
#include <hip/hip_runtime.h>
#include <hip/hip_bf16.h>
#include <math.h>

// Problem constants
#define B_  8
#define T_  2048
#define C_  768
#define HS_ 256

// Split-K flash: q-block = 64 rows, k-tile = 32 keys, chunk = 8 k-tiles
// (256 keys). q-block qb (0..31) has 2qb+2 k-tiles; chunks(qb) = (qb>>2)+1;
// per-batch chunk total = 144; blocks = 8 * 144 = 1152.
#define CHUNKS_PER_BATCH 144
#define NSLOT (CHUNKS_PER_BATCH * B_)   // 1152

typedef float  f32x4  __attribute__((ext_vector_type(4)));
typedef __bf16 bf16x8 __attribute__((ext_vector_type(8)));
typedef __bf16 bf16x4 __attribute__((ext_vector_type(4)));
typedef __bf16 bf16x2 __attribute__((ext_vector_type(2)));

#define MFMA16(a, b, c) __builtin_amdgcn_mfma_f32_16x16x32_bf16((a), (b), (c), 0, 0, 0)

// global->LDS async copy, 16B per lane (dest = wave-uniform base + lane*16)
#define GLOAD_LDS16(gp, lp)                                                     \
    __builtin_amdgcn_global_load_lds(                                           \
        (const __attribute__((address_space(1))) void*)(gp),                    \
        (__attribute__((address_space(3))) void*)(lp), 16, 0, 0)

// cumulative chunk count before q-block qb: g=qb>>2 -> 2g(g+1) + (qb&3)(g+1)
__device__ __forceinline__ int chunk_cum64(int qb) {
    int g = qb >> 2;
    return 2 * g * (g + 1) + (qb & 3) * (g + 1);
}

// ---------------------------------------------------------------------------
// Kernel 0: x fp32 -> bf16 (coalesced, 8 elem/thread)
// ---------------------------------------------------------------------------
__global__ __launch_bounds__(256) void xb_kernel(const float* __restrict__ x,
                                                 __bf16* __restrict__ xb) {
    size_t i = ((size_t)blockIdx.x * 256 + threadIdx.x) * 8;
    f32x4 a = *(const f32x4*)(x + i);
    f32x4 b = *(const f32x4*)(x + i + 4);
    bf16x8 o;
    o[0] = (__bf16)a[0]; o[1] = (__bf16)a[1]; o[2] = (__bf16)a[2]; o[3] = (__bf16)a[3];
    o[4] = (__bf16)b[0]; o[5] = (__bf16)b[1]; o[6] = (__bf16)b[2]; o[7] = (__bf16)b[3];
    *(bf16x8*)(xb + i) = o;
}

// ---------------------------------------------------------------------------
// Kernel 1: weights -> bf16, transposed to [n(768)][k(768)] (Q|K|V stacked).
// Softmax scale * log2(e) folded into Wq.
// ---------------------------------------------------------------------------
__global__ __launch_bounds__(256) void wt_kernel(const float* __restrict__ Wq,
                                                 const float* __restrict__ Wk,
                                                 const float* __restrict__ Wv,
                                                 __bf16* __restrict__ wt_all,
                                                 float qscale) {
    int idx = blockIdx.x * 256 + threadIdx.x;   // [0, 768*256)
    int mat = blockIdx.y;
    const float* W = (mat == 0) ? Wq : ((mat == 1) ? Wk : Wv);
    float scale = (mat == 0) ? qscale : 1.0f;
    int k = idx >> 8;    // 0..767
    int n = idx & 255;   // 0..255
    wt_all[((size_t)mat * HS_ + n) * C_ + k] = (__bf16)(W[idx] * scale);
}

// ---------------------------------------------------------------------------
// Kernel 2: fused QKV GEMM (bf16 in, BK=64 -> 12 k-iters).
// Fragment layouts (element index, all *8 = 8 bf16 per lane slot):
//   Q: ((((b*32+qt)*4 + w16)*8 + ks )*64 + lane)   lane&15 = q, quad = d>>3
//   K: ((((b*32+kt)*8 + ks )*4 + ns )*64 + lane)   lane&15 = s, quad = d>>3
//   V: ((((b*32+kt)*2 + ks2)*16 + ntv)*64 + lane)  lane&15 = d, quad = s>>3
// ---------------------------------------------------------------------------
__global__ __launch_bounds__(256) void proj_kernel(const __bf16* __restrict__ xb,
                                                   const __bf16* __restrict__ wt,
                                                   __bf16* __restrict__ qf_,
                                                   __bf16* __restrict__ kf_,
                                                   __bf16* __restrict__ vf_) {
    __shared__ alignas(16) __bf16 ldsA[128 * 64];   // 16 KB
    __shared__ alignas(16) __bf16 ldsB[128 * 64];   // 16 KB

    const int tid  = threadIdx.x;
    const int w    = tid >> 6;
    const int lane = tid & 63;
    const int cm   = lane & 15;
    const int quad = lane >> 4;
    const int wm   = w & 1;
    const int wn   = w >> 1;
    const int m0   = blockIdx.x * 128;
    const int n0   = blockIdx.y * 128;

    f32x4 acc[4][4];
#pragma unroll
    for (int i = 0; i < 4; i++)
#pragma unroll
        for (int j = 0; j < 4; j++) acc[i][j] = (f32x4){0.f, 0.f, 0.f, 0.f};

    for (int k0 = 0; k0 < C_; k0 += 64) {
        __syncthreads();
#pragma unroll
        for (int h = 0; h < 4; h++) {
            int c = tid + h * 256;
            GLOAD_LDS16(xb + (size_t)(m0 + (c >> 3)) * C_ + k0 + (c & 7) * 8,
                        ldsA + c * 8);
        }
#pragma unroll
        for (int h = 0; h < 4; h++) {
            int c = tid + h * 256;
            GLOAD_LDS16(wt + (size_t)(n0 + (c >> 3)) * C_ + k0 + (c & 7) * 8,
                        ldsB + c * 8);
        }
        __syncthreads();

#pragma unroll
        for (int ks = 0; ks < 2; ks++) {
            bf16x8 af[4], bfr[4];
#pragma unroll
            for (int mt = 0; mt < 4; mt++)
                af[mt] = *(const bf16x8*)&ldsA[(wm * 64 + mt * 16 + cm) * 64 + ks * 32 + quad * 8];
#pragma unroll
            for (int nt = 0; nt < 4; nt++)
                bfr[nt] = *(const bf16x8*)&ldsB[(wn * 64 + nt * 16 + cm) * 64 + ks * 32 + quad * 8];
#pragma unroll
            for (int mt = 0; mt < 4; mt++)
#pragma unroll
                for (int nt = 0; nt < 4; nt++)
                    acc[mt][nt] = MFMA16(af[mt], bfr[nt], acc[mt][nt]);
        }
    }

    const int mat   = n0 >> 8;                 // 0=Q 1=K 2=V
    const int dBase = (n0 & 255) + wn * 64;
    const int b     = m0 >> 11;
    const int rt    = ((m0 & 2047) + wm * 64) >> 6;

    if (mat == 0) {
#pragma unroll
        for (int mt = 0; mt < 4; mt++)
#pragma unroll
            for (int nt = 0; nt < 4; nt++) {
                int ksq   = (dBase >> 5) + (nt >> 1);
                int quad2 = (nt & 1) * 2 + (cm >> 3);
                int j     = cm & 7;
                size_t base = ((((size_t)(b * 32 + rt) * 4 + mt) * 8 + ksq) * 64
                               + quad2 * 16) * 8 + j;
#pragma unroll
                for (int i = 0; i < 4; i++)
                    qf_[base + (quad * 4 + i) * 8] = (__bf16)acc[mt][nt][i];
            }
    } else if (mat == 1) {
#pragma unroll
        for (int mt = 0; mt < 4; mt++)
#pragma unroll
            for (int nt = 0; nt < 4; nt++) {
                int ksq   = (dBase >> 5) + (nt >> 1);
                int quad2 = (nt & 1) * 2 + (cm >> 3);
                int j     = cm & 7;
                size_t base = ((((size_t)(b * 32 + rt) * 8 + ksq) * 4 + mt) * 64
                               + quad2 * 16) * 8 + j;
#pragma unroll
                for (int i = 0; i < 4; i++)
                    kf_[base + (quad * 4 + i) * 8] = (__bf16)acc[mt][nt][i];
            }
    } else {
#pragma unroll
        for (int mt = 0; mt < 4; mt++) {
            int ks2   = (mt >> 1) & 1;
            int quadF = (mt & 1) * 2 + (quad >> 1);
            int jb    = (quad & 1) * 4;
#pragma unroll
            for (int nt = 0; nt < 4; nt++) {
                int ntv = (dBase >> 4) + nt;
                size_t idx = ((((size_t)(b * 32 + rt) * 2 + ks2) * 16 + ntv) * 64
                              + quadF * 16 + cm) * 8 + jb;
                bf16x4 v4;
                v4[0] = (__bf16)acc[mt][nt][0]; v4[1] = (__bf16)acc[mt][nt][1];
                v4[2] = (__bf16)acc[mt][nt][2]; v4[3] = (__bf16)acc[mt][nt][3];
                *(bf16x4*)(vf_ + idx) = v4;
            }
        }
    }
}

// ---------------------------------------------------------------------------
// Kernel 3a: split-K causal flash partial.
//   256 threads (4 waves), q-block = 64 rows (wave = 16 q), k-tile = 32 keys.
//   LDS: K 16 KB + V 16 KB + P 4x1 KB = 36 KB  -> 3 blocks/CU (regs ~160 ->
//   3 waves/SIMD). 2 barriers per tile; 3 independent blocks overlap stalls.
//   QK^T operand-SWAPPED: St = K·Q^T, C-layout col=lane&15=q, row=quad*4+i=s.
//   -> softmax per-lane over 8 regs + 2 shfl_xor steps; scalar m/l per lane.
//   P -> private per-wave 1 KB LDS in PV-A layout; PV: A=P, B=V.
// ---------------------------------------------------------------------------
__global__ __launch_bounds__(256) void flash_part(const __bf16* __restrict__ qf_,
                                                  const __bf16* __restrict__ kf_,
                                                  const __bf16* __restrict__ vf_,
                                                  __bf16* __restrict__ Opart,
                                                  float* __restrict__ mpart,
                                                  float* __restrict__ lpart) {
    __shared__ alignas(16) __bf16 ldsK[8 * 2 * 64 * 8];   // [ks8][ns2][lane]x8 = 16 KB
    __shared__ alignas(16) __bf16 ldsV[16 * 64 * 8];      // [ntv16][lane]x8  = 16 KB
    __shared__ alignas(16) __bf16 ldsP[4][512];           // per-wave P (1 KB)

    const int tid  = threadIdx.x;
    const int w    = tid >> 6;       // 0..3
    const int lane = tid & 63;
    const int cm   = lane & 15;      // = q column (St layout)
    const int quad = lane >> 4;

    const int pid  = blockIdx.x;                // [0, 1152)
    const int b    = pid & 7;                   // batch -> XCD spread
    const int r    = (CHUNKS_PER_BATCH - 1) - (pid >> 3);   // heavy chunks first
    int qb = 0, ci = 0;
    {
        int rr = r;
        for (int j = 0; j < 32; j++) {
            int c = (j >> 2) + 1;
            if (rr < c) { qb = j; ci = rr; break; }
            rr -= c;
        }
    }
    const int lpid = b * CHUNKS_PER_BATCH + r;  // output slot
    const int kt_begin = ci * 8;                        // 32-key tiles
    const int kt_end   = min(kt_begin + 8, 2 * qb + 2);

    // Q fragments (B-operand: lane&15 = q, quad*8+j = d), coalesced loads.
    const __bf16* qp = qf_ + (((size_t)(b * 32 + qb) * 4 + w) * 8) * 512 + lane * 8;
    bf16x8 qf[8];
#pragma unroll
    for (int ks = 0; ks < 8; ks++) qf[ks] = *(const bf16x8*)(qp + ks * 512);

    f32x4 accO[16];
#pragma unroll
    for (int i = 0; i < 16; i++) accO[i] = (f32x4){0.f, 0.f, 0.f, 0.f};
    float mi = -__builtin_inff(), li = 0.f;     // per-lane (q = cm), repl. x4 quads

    const int wrow  = qb * 64 + w * 16;         // wave's first q row (global)
    const int qglob = wrow + cm;                // this lane's q row

    for (int kt = kt_begin; kt < kt_end; kt++) {
        __syncthreads();   // (A) prior tile's LDS fully consumed

        // ---- stage K (16 KB) + V (16 KB) tile, async ----
        {
            const int kt64 = kt >> 1, kh = kt & 1;
            const __bf16* kgb = kf_ + (((size_t)(b * 32 + kt64) * 8) * 4 + kh * 2) * 512;
#pragma unroll
            for (int h = 0; h < 4; h++) {
                int g = h * 256 + tid;           // 16B slot id, 0..1023
                int ks = g >> 7, sub = g & 127;  // sub = ns2*64 + lane'
                GLOAD_LDS16(kgb + (size_t)ks * 4 * 512 + sub * 8,
                            ldsK + (h * 256 + w * 64) * 8);
            }
            const __bf16* vgb = vf_ + ((size_t)(b * 64 + kt) * 16) * 512;
#pragma unroll
            for (int h = 0; h < 4; h++) {
                int g = h * 256 + tid;           // ntv = g>>6, lane' = g&63
                GLOAD_LDS16(vgb + (size_t)g * 8,
                            ldsV + (h * 256 + w * 64) * 8);
            }
        }
        __syncthreads();   // (B) vmcnt drained -> K/V visible

        // ---- St = K Q^T  (32 s x 16 q per wave) ----
        f32x4 s[2];
#pragma unroll
        for (int i = 0; i < 2; i++) s[i] = (f32x4){0.f, 0.f, 0.f, 0.f};
#pragma unroll
        for (int ns = 0; ns < 2; ns++)
#pragma unroll
            for (int ks = 0; ks < 8; ks++) {
                bf16x8 kfr = *(const bf16x8*)&ldsK[(ks * 2 + ns) * 512 + lane * 8];
                s[ns] = MFMA16(kfr, qf[ks], s[ns]);
            }
        // ---- causal mask (s row = kt*32 + ns*16 + quad*4 + i; col q = qglob)
        if (kt * 32 + 31 > wrow) {
#pragma unroll
            for (int ns = 0; ns < 2; ns++)
#pragma unroll
                for (int i = 0; i < 4; i++)
                    if (kt * 32 + ns * 16 + quad * 4 + i > qglob)
                        s[ns][i] = -__builtin_inff();
        }
        // ---- online softmax: per-lane over 8 regs + 2 shfl steps ----
        float pm = -__builtin_inff();
#pragma unroll
        for (int ns = 0; ns < 2; ns++)
#pragma unroll
            for (int i = 0; i < 4; i++) pm = fmaxf(pm, s[ns][i]);
        pm = fmaxf(pm, __shfl_xor(pm, 16));
        pm = fmaxf(pm, __shfl_xor(pm, 32));

        float mn = fmaxf(mi, pm);
        float al = exp2f(mi - mn);
        mi = mn;
        float p[2][4], rs = 0.f;
#pragma unroll
        for (int ns = 0; ns < 2; ns++)
#pragma unroll
            for (int i = 0; i < 4; i++) {
                p[ns][i] = exp2f(s[ns][i] - mn);
                rs += p[ns][i];
            }
        rs += __shfl_xor(rs, 16);
        rs += __shfl_xor(rs, 32);
        li = li * al + rs;

        // ---- rescale accO (rows q = quad*4+i need alpha[q]; bcast via shfl)
        if (__any(al != 1.0f)) {
            float aa[4];
#pragma unroll
            for (int i = 0; i < 4; i++) aa[i] = __shfl(al, quad * 4 + i);
#pragma unroll
            for (int nt = 0; nt < 16; nt++)
#pragma unroll
                for (int i = 0; i < 4; i++) accO[nt][i] *= aa[i];
        }

        // ---- P -> private per-wave LDS in PV-A layout ----
        // element (q, s): offset = ((s>>3)*16 + q)*8 + (s&7); s = ns*16+quad*4+i
#pragma unroll
        for (int ns = 0; ns < 2; ns++)
#pragma unroll
            for (int i2 = 0; i2 < 2; i2++) {
                bf16x2 d2;
                d2[0] = (__bf16)p[ns][2 * i2];
                d2[1] = (__bf16)p[ns][2 * i2 + 1];
                int off = ((ns * 2 + (quad >> 1)) * 16 + cm) * 8
                          + (quad & 1) * 4 + i2 * 2;
                *(bf16x2*)&ldsP[w][off] = d2;
            }
        // ---- O += P V  (A = P frag: k = s = quad*8+j) ----
        bf16x8 pfrag = *(const bf16x8*)&ldsP[w][(quad * 16 + cm) * 8];
#pragma unroll
        for (int nt = 0; nt < 16; nt++) {
            bf16x8 vfr = *(const bf16x8*)&ldsV[(nt * 64 + lane) * 8];
            accO[nt] = MFMA16(pfrag, vfr, accO[nt]);
        }
    }

    // ---- epilogue: unnormalized bf16 partial + fp32 (m, l) ----
    // accO C-layout: col = lane&15 = d-sub, row = quad*4+i = q-sub.
#pragma unroll
    for (int nt = 0; nt < 16; nt++)
#pragma unroll
        for (int i = 0; i < 4; i++)
            Opart[((size_t)lpid * 64 + w * 16 + quad * 4 + i) * HS_ + nt * 16 + cm]
                = (__bf16)accO[nt][i];
    if (quad == 0) {
        mpart[lpid * 64 + w * 16 + cm] = mi;
        lpart[lpid * 64 + w * 16 + cm] = li;
    }
}

// ---------------------------------------------------------------------------
// Kernel 3b: combine partials.  Grid (256, 4): block = (b, qb) x 16 rows.
// ---------------------------------------------------------------------------
__global__ __launch_bounds__(256) void flash_combine(const __bf16* __restrict__ Opart,
                                                     const float* __restrict__ mpart,
                                                     const float* __restrict__ lpart,
                                                     float* __restrict__ out) {
    const int b    = blockIdx.x >> 5;
    const int qb   = blockIdx.x & 31;
    const int nc   = (qb >> 2) + 1;
    const int pid0 = b * CHUNKS_PER_BATCH + chunk_cum64(qb);

    const int tid  = threadIdx.x;
    const int col  = (tid & 63) * 4;
    const int r0   = blockIdx.y * 16 + (tid >> 6) * 4;

    // pass 1: running max over chunks (vector over 4 rows)
    f32x4 ms = (f32x4){-__builtin_inff(), -__builtin_inff(),
                       -__builtin_inff(), -__builtin_inff()};
    for (int c = 0; c < nc; c++) {
        f32x4 m4 = *(const f32x4*)(mpart + (pid0 + c) * 64 + r0);
#pragma unroll
        for (int i = 0; i < 4; i++) ms[i] = fmaxf(ms[i], m4[i]);
    }
    f32x4 acc[4];
#pragma unroll
    for (int i = 0; i < 4; i++) acc[i] = (f32x4){0.f, 0.f, 0.f, 0.f};
    f32x4 lt = (f32x4){0.f, 0.f, 0.f, 0.f};
    for (int c = 0; c < nc; c++) {
        f32x4 m4 = *(const f32x4*)(mpart + (pid0 + c) * 64 + r0);
        f32x4 l4 = *(const f32x4*)(lpart + (pid0 + c) * 64 + r0);
#pragma unroll
        for (int i = 0; i < 4; i++) {
            float sc = exp2f(m4[i] - ms[i]);
            lt[i] += l4[i] * sc;
            bf16x4 o = *(const bf16x4*)(Opart
                        + ((size_t)(pid0 + c) * 64 + r0 + i) * HS_ + col);
            acc[i][0] += (float)o[0] * sc; acc[i][1] += (float)o[1] * sc;
            acc[i][2] += (float)o[2] * sc; acc[i][3] += (float)o[3] * sc;
        }
    }
#pragma unroll
    for (int i = 0; i < 4; i++) {
        float inv = 1.0f / lt[i];
        f32x4 res = (f32x4){acc[i][0] * inv, acc[i][1] * inv,
                            acc[i][2] * inv, acc[i][3] * inv};
        *(f32x4*)(out + ((size_t)(b * T_ + qb * 64 + r0 + i)) * HS_ + col) = res;
    }
}

// ---------------------------------------------------------------------------
extern "C" void kernel_launch(void* const* d_in, const int* in_sizes, int n_in,
                              void* d_out, int out_size, void* d_ws, size_t ws_size,
                              hipStream_t stream) {
    const float* x  = (const float*)d_in[0];
    const float* Wq = (const float*)d_in[1];
    const float* Wk = (const float*)d_in[2];
    const float* Wv = (const float*)d_in[3];
    float* out = (float*)d_out;

    char* ws = (char*)d_ws;
    // ws layout (bytes); xb unioned with Opart (xb dead after proj):
    //   wt_all : 768*768*2            = 1,179,648
    //   qfrag/kfrag/vfrag             = 3 x 8,388,608
    //   union  : xb 25,165,824 | Opart(bf16) 37,748,736; then mpart/lpart
    size_t off = 0;
    __bf16* wt_all = (__bf16*)(ws + off); off += 1179648;
    __bf16* qfrag  = (__bf16*)(ws + off); off += 8388608;
    __bf16* kfrag  = (__bf16*)(ws + off); off += 8388608;
    __bf16* vfrag  = (__bf16*)(ws + off); off += 8388608;
    __bf16* xb     = (__bf16*)(ws + off);              // union with Opart
    __bf16* Opart  = (__bf16*)(ws + off); off += (size_t)NSLOT * 64 * HS_ * 2;
    float*  mpart  = (float*)(ws + off);  off += (size_t)NSLOT * 64 * 4;
    float*  lpart  = (float*)(ws + off);

    float qscale = 1.4426950408889634f / sqrtf((float)C_);

    xb_kernel<<<dim3(6144), 256, 0, stream>>>(x, xb);
    wt_kernel<<<dim3(768, 3), 256, 0, stream>>>(Wq, Wk, Wv, wt_all, qscale);
    proj_kernel<<<dim3(128, 6), 256, 0, stream>>>(xb, wt_all, qfrag, kfrag, vfrag);
    flash_part<<<dim3(NSLOT), 256, 0, stream>>>(qfrag, kfrag, vfrag, Opart, mpart, lpart);
    flash_combine<<<dim3(256, 4), 256, 0, stream>>>(Opart, mpart, lpart, out);
}

// Round 9
// 200.011 us; speedup vs baseline: 1.2123x; 1.0104x over previous
//
#include <hip/hip_runtime.h>
#include <hip/hip_bf16.h>
#include <math.h>

// Problem constants
#define B_  8
#define T_  2048
#define C_  768
#define HS_ 256

// Split-K flash: q-block = 64 rows, k-tile = 32 keys, chunk = 8 k-tiles
// (256 keys). q-block qb (0..31) has 2qb+2 k-tiles; chunks(qb) = (qb>>2)+1;
// per-batch chunk total = 144; blocks = 8 * 144 = 1152.
#define CHUNKS_PER_BATCH 144
#define NSLOT (CHUNKS_PER_BATCH * B_)   // 1152

typedef float  f32x4  __attribute__((ext_vector_type(4)));
typedef __bf16 bf16x8 __attribute__((ext_vector_type(8)));
typedef __bf16 bf16x4 __attribute__((ext_vector_type(4)));
typedef __bf16 bf16x2 __attribute__((ext_vector_type(2)));

#define MFMA16(a, b, c) __builtin_amdgcn_mfma_f32_16x16x32_bf16((a), (b), (c), 0, 0, 0)

// global->LDS async copy, 16B per lane (dest = wave-uniform base + lane*16)
#define GLOAD_LDS16(gp, lp)                                                     \
    __builtin_amdgcn_global_load_lds(                                           \
        (const __attribute__((address_space(1))) void*)(gp),                    \
        (__attribute__((address_space(3))) void*)(lp), 16, 0, 0)

// cumulative chunk count before q-block qb: g=qb>>2 -> 2g(g+1) + (qb&3)(g+1)
__device__ __forceinline__ int chunk_cum64(int qb) {
    int g = qb >> 2;
    return 2 * g * (g + 1) + (qb & 3) * (g + 1);
}

// ---------------------------------------------------------------------------
// Kernel 0: x fp32 -> bf16 (coalesced, 8 elem/thread)
// ---------------------------------------------------------------------------
__global__ __launch_bounds__(256) void xb_kernel(const float* __restrict__ x,
                                                 __bf16* __restrict__ xb) {
    size_t i = ((size_t)blockIdx.x * 256 + threadIdx.x) * 8;
    f32x4 a = *(const f32x4*)(x + i);
    f32x4 b = *(const f32x4*)(x + i + 4);
    bf16x8 o;
    o[0] = (__bf16)a[0]; o[1] = (__bf16)a[1]; o[2] = (__bf16)a[2]; o[3] = (__bf16)a[3];
    o[4] = (__bf16)b[0]; o[5] = (__bf16)b[1]; o[6] = (__bf16)b[2]; o[7] = (__bf16)b[3];
    *(bf16x8*)(xb + i) = o;
}

// ---------------------------------------------------------------------------
// Kernel 1: weights -> bf16, transposed to [n(768)][k(768)] (Q|K|V stacked).
// Softmax scale * log2(e) folded into Wq.
// ---------------------------------------------------------------------------
__global__ __launch_bounds__(256) void wt_kernel(const float* __restrict__ Wq,
                                                 const float* __restrict__ Wk,
                                                 const float* __restrict__ Wv,
                                                 __bf16* __restrict__ wt_all,
                                                 float qscale) {
    int idx = blockIdx.x * 256 + threadIdx.x;   // [0, 768*256)
    int mat = blockIdx.y;
    const float* W = (mat == 0) ? Wq : ((mat == 1) ? Wk : Wv);
    float scale = (mat == 0) ? qscale : 1.0f;
    int k = idx >> 8;    // 0..767
    int n = idx & 255;   // 0..255
    wt_all[((size_t)mat * HS_ + n) * C_ + k] = (__bf16)(W[idx] * scale);
}

// ---------------------------------------------------------------------------
// Kernel 2: fused QKV GEMM (bf16 in, BK=64 -> 12 k-iters).
//   Q/K tiles: MFMA operands SWAPPED (acc = B x A) so C-rows (quad*4+i)
//   carry the d-dimension -> per-lane bf16x4 stores, each store instruction
//   covers a contiguous 1 KB fragment region (was: 64 scattered 2B stores).
//   V keeps original order (its layout already gives coalesced bf16x4).
// Fragment layouts (element index, all *8 = 8 bf16 per lane slot):
//   Q: ((((b*32+qt)*4 + w16)*8 + ks )*64 + lane)   lane&15 = q, quad = (d>>3)&3, j = d&7
//   K: ((((b*32+kt)*8 + ks )*4 + ns )*64 + lane)   lane&15 = s, quad = (d>>3)&3, j = d&7
//   V: ((((b*32+kt)*2 + ks2)*16 + ntv)*64 + lane)  lane&15 = d, quad = (s>>3)&3, j = s&7
// ---------------------------------------------------------------------------
__global__ __launch_bounds__(256) void proj_kernel(const __bf16* __restrict__ xb,
                                                   const __bf16* __restrict__ wt,
                                                   __bf16* __restrict__ qf_,
                                                   __bf16* __restrict__ kf_,
                                                   __bf16* __restrict__ vf_) {
    __shared__ alignas(16) __bf16 ldsA[128 * 64];   // 16 KB
    __shared__ alignas(16) __bf16 ldsB[128 * 64];   // 16 KB

    const int tid  = threadIdx.x;
    const int w    = tid >> 6;
    const int lane = tid & 63;
    const int cm   = lane & 15;
    const int quad = lane >> 4;
    const int wm   = w & 1;
    const int wn   = w >> 1;
    const int m0   = blockIdx.x * 128;
    const int n0   = blockIdx.y * 128;
    const int mat  = n0 >> 8;                 // 0=Q 1=K 2=V

    f32x4 acc[4][4];
#pragma unroll
    for (int i = 0; i < 4; i++)
#pragma unroll
        for (int j = 0; j < 4; j++) acc[i][j] = (f32x4){0.f, 0.f, 0.f, 0.f};

    if (mat < 2) {
        // ---------------- Q/K path: swapped operands ----------------
        for (int k0 = 0; k0 < C_; k0 += 64) {
            __syncthreads();
#pragma unroll
            for (int h = 0; h < 4; h++) {
                int c = tid + h * 256;
                GLOAD_LDS16(xb + (size_t)(m0 + (c >> 3)) * C_ + k0 + (c & 7) * 8,
                            ldsA + c * 8);
            }
#pragma unroll
            for (int h = 0; h < 4; h++) {
                int c = tid + h * 256;
                GLOAD_LDS16(wt + (size_t)(n0 + (c >> 3)) * C_ + k0 + (c & 7) * 8,
                            ldsB + c * 8);
            }
            __syncthreads();

#pragma unroll
            for (int ks = 0; ks < 2; ks++) {
                bf16x8 af[4], bfr[4];
#pragma unroll
                for (int mt = 0; mt < 4; mt++)
                    af[mt] = *(const bf16x8*)&ldsA[(wm * 64 + mt * 16 + cm) * 64 + ks * 32 + quad * 8];
#pragma unroll
                for (int nt = 0; nt < 4; nt++)
                    bfr[nt] = *(const bf16x8*)&ldsB[(wn * 64 + nt * 16 + cm) * 64 + ks * 32 + quad * 8];
                // acc[dt][qt2] = wt-frag x x-frag : C-row = d, C-col = q-row
#pragma unroll
                for (int dt = 0; dt < 4; dt++)
#pragma unroll
                    for (int qt2 = 0; qt2 < 4; qt2++)
                        acc[dt][qt2] = MFMA16(bfr[dt], af[qt2], acc[dt][qt2]);
            }
        }
        // ---- epilogue: coalesced bf16x4 stores ----
        const int dBase = (n0 & 255) + wn * 64;
        const int b     = m0 >> 11;
        const int rt2   = ((m0 & 2047) >> 6) + wm;   // 64-row tile within batch
        __bf16* dst = (mat == 0) ? qf_ : kf_;
#pragma unroll
        for (int dt = 0; dt < 4; dt++)
#pragma unroll
            for (int qt2 = 0; qt2 < 4; qt2++) {
                int d0    = dBase + dt * 16 + quad * 4;   // d of reg i = d0 + i
                int ksq   = d0 >> 5;
                int quadp = (d0 >> 3) & 3;
                int j0    = d0 & 7;
                size_t addr;
                if (mat == 0)
                    addr = ((((size_t)(b * 32 + rt2) * 4 + qt2) * 8 + ksq) * 64
                            + quadp * 16 + cm) * 8 + j0;
                else
                    addr = ((((size_t)(b * 32 + rt2) * 8 + ksq) * 4 + qt2) * 64
                            + quadp * 16 + cm) * 8 + j0;
                bf16x4 v4;
                v4[0] = (__bf16)acc[dt][qt2][0]; v4[1] = (__bf16)acc[dt][qt2][1];
                v4[2] = (__bf16)acc[dt][qt2][2]; v4[3] = (__bf16)acc[dt][qt2][3];
                *(bf16x4*)(dst + addr) = v4;
            }
    } else {
        // ---------------- V path: original operand order ----------------
        for (int k0 = 0; k0 < C_; k0 += 64) {
            __syncthreads();
#pragma unroll
            for (int h = 0; h < 4; h++) {
                int c = tid + h * 256;
                GLOAD_LDS16(xb + (size_t)(m0 + (c >> 3)) * C_ + k0 + (c & 7) * 8,
                            ldsA + c * 8);
            }
#pragma unroll
            for (int h = 0; h < 4; h++) {
                int c = tid + h * 256;
                GLOAD_LDS16(wt + (size_t)(n0 + (c >> 3)) * C_ + k0 + (c & 7) * 8,
                            ldsB + c * 8);
            }
            __syncthreads();

#pragma unroll
            for (int ks = 0; ks < 2; ks++) {
                bf16x8 af[4], bfr[4];
#pragma unroll
                for (int mt = 0; mt < 4; mt++)
                    af[mt] = *(const bf16x8*)&ldsA[(wm * 64 + mt * 16 + cm) * 64 + ks * 32 + quad * 8];
#pragma unroll
                for (int nt = 0; nt < 4; nt++)
                    bfr[nt] = *(const bf16x8*)&ldsB[(wn * 64 + nt * 16 + cm) * 64 + ks * 32 + quad * 8];
#pragma unroll
                for (int mt = 0; mt < 4; mt++)
#pragma unroll
                    for (int nt = 0; nt < 4; nt++)
                        acc[mt][nt] = MFMA16(af[mt], bfr[nt], acc[mt][nt]);
            }
        }
        const int dBase = (n0 & 255) + wn * 64;
        const int b     = m0 >> 11;
        const int rt    = ((m0 & 2047) + wm * 64) >> 6;
#pragma unroll
        for (int mt = 0; mt < 4; mt++) {
            int ks2   = (mt >> 1) & 1;
            int quadF = (mt & 1) * 2 + (quad >> 1);
            int jb    = (quad & 1) * 4;
#pragma unroll
            for (int nt = 0; nt < 4; nt++) {
                int ntv = (dBase >> 4) + nt;
                size_t idx = ((((size_t)(b * 32 + rt) * 2 + ks2) * 16 + ntv) * 64
                              + quadF * 16 + cm) * 8 + jb;
                bf16x4 v4;
                v4[0] = (__bf16)acc[mt][nt][0]; v4[1] = (__bf16)acc[mt][nt][1];
                v4[2] = (__bf16)acc[mt][nt][2]; v4[3] = (__bf16)acc[mt][nt][3];
                *(bf16x4*)(vf_ + idx) = v4;
            }
        }
    }
}

// ---------------------------------------------------------------------------
// Kernel 3a: split-K causal flash partial.
//   256 threads (4 waves), q-block = 64 rows (wave = 16 q), k-tile = 32 keys.
//   LDS: K 16 KB + V 16 KB + P 4x1 KB = 36 KB. 2 barriers per tile.
//   QK^T operand-SWAPPED: St = K·Q^T, C col=lane&15=q, row=quad*4+i=s.
// ---------------------------------------------------------------------------
__global__ __launch_bounds__(256) void flash_part(const __bf16* __restrict__ qf_,
                                                  const __bf16* __restrict__ kf_,
                                                  const __bf16* __restrict__ vf_,
                                                  __bf16* __restrict__ Opart,
                                                  float* __restrict__ mpart,
                                                  float* __restrict__ lpart) {
    __shared__ alignas(16) __bf16 ldsK[8 * 2 * 64 * 8];   // [ks8][ns2][lane]x8 = 16 KB
    __shared__ alignas(16) __bf16 ldsV[16 * 64 * 8];      // [ntv16][lane]x8  = 16 KB
    __shared__ alignas(16) __bf16 ldsP[4][512];           // per-wave P (1 KB)

    const int tid  = threadIdx.x;
    const int w    = tid >> 6;       // 0..3
    const int lane = tid & 63;
    const int cm   = lane & 15;      // = q column (St layout)
    const int quad = lane >> 4;

    const int pid  = blockIdx.x;                // [0, 1152)
    const int b    = pid & 7;                   // batch -> XCD spread
    const int r    = (CHUNKS_PER_BATCH - 1) - (pid >> 3);   // heavy chunks first
    int qb = 0, ci = 0;
    {
        int rr = r;
        for (int j = 0; j < 32; j++) {
            int c = (j >> 2) + 1;
            if (rr < c) { qb = j; ci = rr; break; }
            rr -= c;
        }
    }
    const int lpid = b * CHUNKS_PER_BATCH + r;  // output slot
    const int kt_begin = ci * 8;                        // 32-key tiles
    const int kt_end   = min(kt_begin + 8, 2 * qb + 2);

    // Q fragments (B-operand: lane&15 = q, quad*8+j = d), coalesced loads.
    const __bf16* qp = qf_ + (((size_t)(b * 32 + qb) * 4 + w) * 8) * 512 + lane * 8;
    bf16x8 qf[8];
#pragma unroll
    for (int ks = 0; ks < 8; ks++) qf[ks] = *(const bf16x8*)(qp + ks * 512);

    f32x4 accO[16];
#pragma unroll
    for (int i = 0; i < 16; i++) accO[i] = (f32x4){0.f, 0.f, 0.f, 0.f};
    float mi = -__builtin_inff(), li = 0.f;     // per-lane (q = cm), repl. x4 quads

    const int wrow  = qb * 64 + w * 16;         // wave's first q row (global)
    const int qglob = wrow + cm;                // this lane's q row

    for (int kt = kt_begin; kt < kt_end; kt++) {
        __syncthreads();   // (A) prior tile's LDS fully consumed

        // ---- stage K (16 KB) + V (16 KB) tile, async ----
        {
            const int kt64 = kt >> 1, kh = kt & 1;
            const __bf16* kgb = kf_ + (((size_t)(b * 32 + kt64) * 8) * 4 + kh * 2) * 512;
#pragma unroll
            for (int h = 0; h < 4; h++) {
                int g = h * 256 + tid;           // 16B slot id, 0..1023
                int ks = g >> 7, sub = g & 127;  // sub = ns2*64 + lane'
                GLOAD_LDS16(kgb + (size_t)ks * 4 * 512 + sub * 8,
                            ldsK + (h * 256 + w * 64) * 8);
            }
            const __bf16* vgb = vf_ + ((size_t)(b * 64 + kt) * 16) * 512;
#pragma unroll
            for (int h = 0; h < 4; h++) {
                int g = h * 256 + tid;           // ntv = g>>6, lane' = g&63
                GLOAD_LDS16(vgb + (size_t)g * 8,
                            ldsV + (h * 256 + w * 64) * 8);
            }
        }
        __syncthreads();   // (B) vmcnt drained -> K/V visible

        // ---- St = K Q^T  (32 s x 16 q per wave) ----
        f32x4 s[2];
#pragma unroll
        for (int i = 0; i < 2; i++) s[i] = (f32x4){0.f, 0.f, 0.f, 0.f};
#pragma unroll
        for (int ns = 0; ns < 2; ns++)
#pragma unroll
            for (int ks = 0; ks < 8; ks++) {
                bf16x8 kfr = *(const bf16x8*)&ldsK[(ks * 2 + ns) * 512 + lane * 8];
                s[ns] = MFMA16(kfr, qf[ks], s[ns]);
            }
        // ---- causal mask (s row = kt*32 + ns*16 + quad*4 + i; col q = qglob)
        if (kt * 32 + 31 > wrow) {
#pragma unroll
            for (int ns = 0; ns < 2; ns++)
#pragma unroll
                for (int i = 0; i < 4; i++)
                    if (kt * 32 + ns * 16 + quad * 4 + i > qglob)
                        s[ns][i] = -__builtin_inff();
        }
        // ---- online softmax: per-lane over 8 regs + 2 shfl steps ----
        float pm = -__builtin_inff();
#pragma unroll
        for (int ns = 0; ns < 2; ns++)
#pragma unroll
            for (int i = 0; i < 4; i++) pm = fmaxf(pm, s[ns][i]);
        pm = fmaxf(pm, __shfl_xor(pm, 16));
        pm = fmaxf(pm, __shfl_xor(pm, 32));

        float mn = fmaxf(mi, pm);
        float al = exp2f(mi - mn);
        mi = mn;
        float p[2][4], rs = 0.f;
#pragma unroll
        for (int ns = 0; ns < 2; ns++)
#pragma unroll
            for (int i = 0; i < 4; i++) {
                p[ns][i] = exp2f(s[ns][i] - mn);
                rs += p[ns][i];
            }
        rs += __shfl_xor(rs, 16);
        rs += __shfl_xor(rs, 32);
        li = li * al + rs;

        // ---- rescale accO (rows q = quad*4+i need alpha[q]; bcast via shfl)
        if (__any(al != 1.0f)) {
            float aa[4];
#pragma unroll
            for (int i = 0; i < 4; i++) aa[i] = __shfl(al, quad * 4 + i);
#pragma unroll
            for (int nt = 0; nt < 16; nt++)
#pragma unroll
                for (int i = 0; i < 4; i++) accO[nt][i] *= aa[i];
        }

        // ---- P -> private per-wave LDS in PV-A layout ----
#pragma unroll
        for (int ns = 0; ns < 2; ns++)
#pragma unroll
            for (int i2 = 0; i2 < 2; i2++) {
                bf16x2 d2;
                d2[0] = (__bf16)p[ns][2 * i2];
                d2[1] = (__bf16)p[ns][2 * i2 + 1];
                int off = ((ns * 2 + (quad >> 1)) * 16 + cm) * 8
                          + (quad & 1) * 4 + i2 * 2;
                *(bf16x2*)&ldsP[w][off] = d2;
            }
        // ---- O += P V  (A = P frag: k = s = quad*8+j) ----
        bf16x8 pfrag = *(const bf16x8*)&ldsP[w][(quad * 16 + cm) * 8];
#pragma unroll
        for (int nt = 0; nt < 16; nt++) {
            bf16x8 vfr = *(const bf16x8*)&ldsV[(nt * 64 + lane) * 8];
            accO[nt] = MFMA16(pfrag, vfr, accO[nt]);
        }
    }

    // ---- epilogue: unnormalized bf16 partial + fp32 (m, l) ----
#pragma unroll
    for (int nt = 0; nt < 16; nt++)
#pragma unroll
        for (int i = 0; i < 4; i++)
            Opart[((size_t)lpid * 64 + w * 16 + quad * 4 + i) * HS_ + nt * 16 + cm]
                = (__bf16)accO[nt][i];
    if (quad == 0) {
        mpart[lpid * 64 + w * 16 + cm] = mi;
        lpart[lpid * 64 + w * 16 + cm] = li;
    }
}

// ---------------------------------------------------------------------------
// Kernel 3b: combine partials.  Grid (256, 4): block = (b, qb) x 16 rows.
// ---------------------------------------------------------------------------
__global__ __launch_bounds__(256) void flash_combine(const __bf16* __restrict__ Opart,
                                                     const float* __restrict__ mpart,
                                                     const float* __restrict__ lpart,
                                                     float* __restrict__ out) {
    const int b    = blockIdx.x >> 5;
    const int qb   = blockIdx.x & 31;
    const int nc   = (qb >> 2) + 1;
    const int pid0 = b * CHUNKS_PER_BATCH + chunk_cum64(qb);

    const int tid  = threadIdx.x;
    const int col  = (tid & 63) * 4;
    const int r0   = blockIdx.y * 16 + (tid >> 6) * 4;

    f32x4 ms = (f32x4){-__builtin_inff(), -__builtin_inff(),
                       -__builtin_inff(), -__builtin_inff()};
    for (int c = 0; c < nc; c++) {
        f32x4 m4 = *(const f32x4*)(mpart + (pid0 + c) * 64 + r0);
#pragma unroll
        for (int i = 0; i < 4; i++) ms[i] = fmaxf(ms[i], m4[i]);
    }
    f32x4 acc[4];
#pragma unroll
    for (int i = 0; i < 4; i++) acc[i] = (f32x4){0.f, 0.f, 0.f, 0.f};
    f32x4 lt = (f32x4){0.f, 0.f, 0.f, 0.f};
    for (int c = 0; c < nc; c++) {
        f32x4 m4 = *(const f32x4*)(mpart + (pid0 + c) * 64 + r0);
        f32x4 l4 = *(const f32x4*)(lpart + (pid0 + c) * 64 + r0);
#pragma unroll
        for (int i = 0; i < 4; i++) {
            float sc = exp2f(m4[i] - ms[i]);
            lt[i] += l4[i] * sc;
            bf16x4 o = *(const bf16x4*)(Opart
                        + ((size_t)(pid0 + c) * 64 + r0 + i) * HS_ + col);
            acc[i][0] += (float)o[0] * sc; acc[i][1] += (float)o[1] * sc;
            acc[i][2] += (float)o[2] * sc; acc[i][3] += (float)o[3] * sc;
        }
    }
#pragma unroll
    for (int i = 0; i < 4; i++) {
        float inv = 1.0f / lt[i];
        f32x4 res = (f32x4){acc[i][0] * inv, acc[i][1] * inv,
                            acc[i][2] * inv, acc[i][3] * inv};
        *(f32x4*)(out + ((size_t)(b * T_ + qb * 64 + r0 + i)) * HS_ + col) = res;
    }
}

// ---------------------------------------------------------------------------
extern "C" void kernel_launch(void* const* d_in, const int* in_sizes, int n_in,
                              void* d_out, int out_size, void* d_ws, size_t ws_size,
                              hipStream_t stream) {
    const float* x  = (const float*)d_in[0];
    const float* Wq = (const float*)d_in[1];
    const float* Wk = (const float*)d_in[2];
    const float* Wv = (const float*)d_in[3];
    float* out = (float*)d_out;

    char* ws = (char*)d_ws;
    size_t off = 0;
    __bf16* wt_all = (__bf16*)(ws + off); off += 1179648;
    __bf16* qfrag  = (__bf16*)(ws + off); off += 8388608;
    __bf16* kfrag  = (__bf16*)(ws + off); off += 8388608;
    __bf16* vfrag  = (__bf16*)(ws + off); off += 8388608;
    __bf16* xb     = (__bf16*)(ws + off);              // union with Opart
    __bf16* Opart  = (__bf16*)(ws + off); off += (size_t)NSLOT * 64 * HS_ * 2;
    float*  mpart  = (float*)(ws + off);  off += (size_t)NSLOT * 64 * 4;
    float*  lpart  = (float*)(ws + off);

    float qscale = 1.4426950408889634f / sqrtf((float)C_);

    xb_kernel<<<dim3(6144), 256, 0, stream>>>(x, xb);
    wt_kernel<<<dim3(768, 3), 256, 0, stream>>>(Wq, Wk, Wv, wt_all, qscale);
    proj_kernel<<<dim3(128, 6), 256, 0, stream>>>(xb, wt_all, qfrag, kfrag, vfrag);
    flash_part<<<dim3(NSLOT), 256, 0, stream>>>(qfrag, kfrag, vfrag, Opart, mpart, lpart);
    flash_combine<<<dim3(256, 4), 256, 0, stream>>>(Opart, mpart, lpart, out);
}

// Round 10
// 191.983 us; speedup vs baseline: 1.2630x; 1.0418x over previous
//
#include <hip/hip_runtime.h>
#include <hip/hip_bf16.h>
#include <math.h>

// Problem constants
#define B_  8
#define T_  2048
#define C_  768
#define HS_ 256

// Split-K flash: q-block = 64 rows, k-tile = 32 keys, chunk = 8 k-tiles
// (256 keys). q-block qb (0..31) has 2qb+2 k-tiles; chunks(qb) = (qb>>2)+1;
// per-batch chunk total = 144; blocks = 8 * 144 = 1152.
#define CHUNKS_PER_BATCH 144
#define NSLOT (CHUNKS_PER_BATCH * B_)   // 1152

typedef float  f32x4  __attribute__((ext_vector_type(4)));
typedef __bf16 bf16x8 __attribute__((ext_vector_type(8)));
typedef __bf16 bf16x4 __attribute__((ext_vector_type(4)));
typedef __bf16 bf16x2 __attribute__((ext_vector_type(2)));

#define MFMA16(a, b, c) __builtin_amdgcn_mfma_f32_16x16x32_bf16((a), (b), (c), 0, 0, 0)

// global->LDS async copy, 16B per lane (dest = wave-uniform base + lane*16)
#define GLOAD_LDS16(gp, lp)                                                     \
    __builtin_amdgcn_global_load_lds(                                           \
        (const __attribute__((address_space(1))) void*)(gp),                    \
        (__attribute__((address_space(3))) void*)(lp), 16, 0, 0)

// cumulative chunk count before q-block qb: g=qb>>2 -> 2g(g+1) + (qb&3)(g+1)
__device__ __forceinline__ int chunk_cum64(int qb) {
    int g = qb >> 2;
    return 2 * g * (g + 1) + (qb & 3) * (g + 1);
}

// ---------------------------------------------------------------------------
// Kernel 0: prep = x cast (blocks 0..6143) + weight transpose (6144..6431).
//   wt part: thread = (mat, k8, n-lane): reads W[(k8*8+j)*256+n] (coalesced
//   256B across lanes per j), writes one bf16x8 (16B) -- no 2B scatter.
// ---------------------------------------------------------------------------
__global__ __launch_bounds__(256) void prep_kernel(const float* __restrict__ x,
                                                   const float* __restrict__ Wq,
                                                   const float* __restrict__ Wk,
                                                   const float* __restrict__ Wv,
                                                   __bf16* __restrict__ xb,
                                                   __bf16* __restrict__ wt_all,
                                                   float qscale) {
    const int bid = blockIdx.x;
    if (bid < 6144) {
        size_t i = ((size_t)bid * 256 + threadIdx.x) * 8;
        f32x4 a = *(const f32x4*)(x + i);
        f32x4 b = *(const f32x4*)(x + i + 4);
        bf16x8 o;
        o[0] = (__bf16)a[0]; o[1] = (__bf16)a[1]; o[2] = (__bf16)a[2]; o[3] = (__bf16)a[3];
        o[4] = (__bf16)b[0]; o[5] = (__bf16)b[1]; o[6] = (__bf16)b[2]; o[7] = (__bf16)b[3];
        *(bf16x8*)(xb + i) = o;
    } else {
        int idx = (bid - 6144) * 256 + threadIdx.x;   // [0, 73728)
        int n   = idx & 255;
        int t   = idx >> 8;          // [0, 288) = mat*96 + k8
        int mat = t / 96;
        int k8  = t - mat * 96;
        const float* W = (mat == 0) ? Wq : ((mat == 1) ? Wk : Wv);
        float scale = (mat == 0) ? qscale : 1.0f;
        bf16x8 o;
#pragma unroll
        for (int j = 0; j < 8; j++)
            o[j] = (__bf16)(W[(k8 * 8 + j) * HS_ + n] * scale);
        *(bf16x8*)&wt_all[((size_t)mat * HS_ + n) * C_ + k8 * 8] = o;
    }
}

// ---------------------------------------------------------------------------
// Kernel 2: fused QKV GEMM. BK=32, DOUBLE-BUFFERED LDS (2 x 16 KB), ONE
//   barrier per k-iter: prefetch of iter kt+1 issues before compute of kt.
//   Q/K tiles: swapped operands (C rows carry d) -> coalesced bf16x4 stores.
// Fragment layouts (element index, all *8 = 8 bf16 per lane slot):
//   Q: ((((b*32+qt)*4 + w16)*8 + ks )*64 + lane)   lane&15 = q, quad = (d>>3)&3, j = d&7
//   K: ((((b*32+kt)*8 + ks )*4 + ns )*64 + lane)   lane&15 = s, quad = (d>>3)&3, j = d&7
//   V: ((((b*32+kt)*2 + ks2)*16 + ntv)*64 + lane)  lane&15 = d, quad = (s>>3)&3, j = s&7
// ---------------------------------------------------------------------------
__global__ __launch_bounds__(256) void proj_kernel(const __bf16* __restrict__ xb,
                                                   const __bf16* __restrict__ wt,
                                                   __bf16* __restrict__ qf_,
                                                   __bf16* __restrict__ kf_,
                                                   __bf16* __restrict__ vf_) {
    __shared__ alignas(16) __bf16 ldsA[2][128 * 32];   // 2 x 8 KB
    __shared__ alignas(16) __bf16 ldsB[2][128 * 32];   // 2 x 8 KB

    const int tid  = threadIdx.x;
    const int w    = tid >> 6;
    const int lane = tid & 63;
    const int cm   = lane & 15;
    const int quad = lane >> 4;
    const int wm   = w & 1;
    const int wn   = w >> 1;
    const int m0   = blockIdx.x * 128;
    const int n0   = blockIdx.y * 128;
    const int mat  = n0 >> 8;                 // 0=Q 1=K 2=V

    f32x4 acc[4][4];
#pragma unroll
    for (int i = 0; i < 4; i++)
#pragma unroll
        for (int j = 0; j < 4; j++) acc[i][j] = (f32x4){0.f, 0.f, 0.f, 0.f};

    // prologue: stage k-iter 0 into buffer 0
#pragma unroll
    for (int h = 0; h < 2; h++) {
        int c = tid + h * 256;   // 512 chunks: row = c>>2, col granule = (c&3)*8
        GLOAD_LDS16(xb + (size_t)(m0 + (c >> 2)) * C_ + (c & 3) * 8, &ldsA[0][c * 8]);
        GLOAD_LDS16(wt + (size_t)(n0 + (c >> 2)) * C_ + (c & 3) * 8, &ldsB[0][c * 8]);
    }

    for (int kt = 0; kt < 24; kt++) {
        const int cur = kt & 1;
        __syncthreads();   // drains vmcnt -> buf[cur] staged; prev reads done

        if (kt < 23) {
            const int k0 = (kt + 1) * 32;
#pragma unroll
            for (int h = 0; h < 2; h++) {
                int c = tid + h * 256;
                GLOAD_LDS16(xb + (size_t)(m0 + (c >> 2)) * C_ + k0 + (c & 3) * 8,
                            &ldsA[cur ^ 1][c * 8]);
                GLOAD_LDS16(wt + (size_t)(n0 + (c >> 2)) * C_ + k0 + (c & 3) * 8,
                            &ldsB[cur ^ 1][c * 8]);
            }
        }

        bf16x8 af[4], bfr[4];
#pragma unroll
        for (int mt = 0; mt < 4; mt++)
            af[mt] = *(const bf16x8*)&ldsA[cur][(wm * 64 + mt * 16 + cm) * 32 + quad * 8];
#pragma unroll
        for (int nt = 0; nt < 4; nt++)
            bfr[nt] = *(const bf16x8*)&ldsB[cur][(wn * 64 + nt * 16 + cm) * 32 + quad * 8];
        if (mat < 2) {
            // acc[dt][qt2] = wt-frag x x-frag : C-row = d, C-col = q
#pragma unroll
            for (int dt = 0; dt < 4; dt++)
#pragma unroll
                for (int qt2 = 0; qt2 < 4; qt2++)
                    acc[dt][qt2] = MFMA16(bfr[dt], af[qt2], acc[dt][qt2]);
        } else {
#pragma unroll
            for (int mt = 0; mt < 4; mt++)
#pragma unroll
                for (int nt = 0; nt < 4; nt++)
                    acc[mt][nt] = MFMA16(af[mt], bfr[nt], acc[mt][nt]);
        }
    }

    const int dBase = (n0 & 255) + wn * 64;
    const int b     = m0 >> 11;
    if (mat < 2) {
        const int rt2 = ((m0 & 2047) >> 6) + wm;   // 64-row tile within batch
        __bf16* dst = (mat == 0) ? qf_ : kf_;
#pragma unroll
        for (int dt = 0; dt < 4; dt++)
#pragma unroll
            for (int qt2 = 0; qt2 < 4; qt2++) {
                int d0    = dBase + dt * 16 + quad * 4;   // d of reg i = d0 + i
                int ksq   = d0 >> 5;
                int quadp = (d0 >> 3) & 3;
                int j0    = d0 & 7;
                size_t addr;
                if (mat == 0)
                    addr = ((((size_t)(b * 32 + rt2) * 4 + qt2) * 8 + ksq) * 64
                            + quadp * 16 + cm) * 8 + j0;
                else
                    addr = ((((size_t)(b * 32 + rt2) * 8 + ksq) * 4 + qt2) * 64
                            + quadp * 16 + cm) * 8 + j0;
                bf16x4 v4;
                v4[0] = (__bf16)acc[dt][qt2][0]; v4[1] = (__bf16)acc[dt][qt2][1];
                v4[2] = (__bf16)acc[dt][qt2][2]; v4[3] = (__bf16)acc[dt][qt2][3];
                *(bf16x4*)(dst + addr) = v4;
            }
    } else {
        const int rt = ((m0 & 2047) + wm * 64) >> 6;
#pragma unroll
        for (int mt = 0; mt < 4; mt++) {
            int ks2   = (mt >> 1) & 1;
            int quadF = (mt & 1) * 2 + (quad >> 1);
            int jb    = (quad & 1) * 4;
#pragma unroll
            for (int nt = 0; nt < 4; nt++) {
                int ntv = (dBase >> 4) + nt;
                size_t idx = ((((size_t)(b * 32 + rt) * 2 + ks2) * 16 + ntv) * 64
                              + quadF * 16 + cm) * 8 + jb;
                bf16x4 v4;
                v4[0] = (__bf16)acc[mt][nt][0]; v4[1] = (__bf16)acc[mt][nt][1];
                v4[2] = (__bf16)acc[mt][nt][2]; v4[3] = (__bf16)acc[mt][nt][3];
                *(bf16x4*)(vf_ + idx) = v4;
            }
        }
    }
}

// ---------------------------------------------------------------------------
// Kernel 3a: split-K causal flash partial.
//   256 threads (4 waves), q-block = 64 rows, k-tile = 32 keys.
//   QK^T swapped: St = K·Q^T, C col = q = cm -> per-lane softmax.
//   PV ALSO swapped: accO = V-frag x P-frag -> C col = q = cm: rescale is a
//   plain per-lane multiply (no shfl broadcast), epilogue = 16 coalesced
//   bf16x4 stores (was 64 scattered 2B stores).
// ---------------------------------------------------------------------------
__global__ __launch_bounds__(256) void flash_part(const __bf16* __restrict__ qf_,
                                                  const __bf16* __restrict__ kf_,
                                                  const __bf16* __restrict__ vf_,
                                                  __bf16* __restrict__ Opart,
                                                  float* __restrict__ mpart,
                                                  float* __restrict__ lpart) {
    __shared__ alignas(16) __bf16 ldsK[8 * 2 * 64 * 8];   // 16 KB
    __shared__ alignas(16) __bf16 ldsV[16 * 64 * 8];      // 16 KB
    __shared__ alignas(16) __bf16 ldsP[4][512];           // per-wave P (1 KB)

    const int tid  = threadIdx.x;
    const int w    = tid >> 6;       // 0..3
    const int lane = tid & 63;
    const int cm   = lane & 15;      // = q column
    const int quad = lane >> 4;

    const int pid  = blockIdx.x;                // [0, 1152)
    const int b    = pid & 7;                   // batch -> XCD spread
    const int r    = (CHUNKS_PER_BATCH - 1) - (pid >> 3);   // heavy chunks first
    int qb = 0, ci = 0;
    {
        int rr = r;
        for (int j = 0; j < 32; j++) {
            int c = (j >> 2) + 1;
            if (rr < c) { qb = j; ci = rr; break; }
            rr -= c;
        }
    }
    const int lpid = b * CHUNKS_PER_BATCH + r;  // output slot
    const int kt_begin = ci * 8;                        // 32-key tiles
    const int kt_end   = min(kt_begin + 8, 2 * qb + 2);

    // Q fragments (B-operand: lane&15 = q, quad*8+j = d), coalesced loads.
    const __bf16* qp = qf_ + (((size_t)(b * 32 + qb) * 4 + w) * 8) * 512 + lane * 8;
    bf16x8 qf[8];
#pragma unroll
    for (int ks = 0; ks < 8; ks++) qf[ks] = *(const bf16x8*)(qp + ks * 512);

    f32x4 accO[16];   // accO[nt][i]: d = nt*16 + quad*4 + i, q = cm
#pragma unroll
    for (int i = 0; i < 16; i++) accO[i] = (f32x4){0.f, 0.f, 0.f, 0.f};
    float mi = -__builtin_inff(), li = 0.f;     // per-lane (q = cm)

    const int wrow  = qb * 64 + w * 16;
    const int qglob = wrow + cm;

    for (int kt = kt_begin; kt < kt_end; kt++) {
        __syncthreads();   // (A) prior tile's LDS fully consumed

        // ---- stage K (16 KB) + V (16 KB) tile, async ----
        {
            const int kt64 = kt >> 1, kh = kt & 1;
            const __bf16* kgb = kf_ + (((size_t)(b * 32 + kt64) * 8) * 4 + kh * 2) * 512;
#pragma unroll
            for (int h = 0; h < 4; h++) {
                int g = h * 256 + tid;
                int ks = g >> 7, sub = g & 127;
                GLOAD_LDS16(kgb + (size_t)ks * 4 * 512 + sub * 8,
                            ldsK + (h * 256 + w * 64) * 8);
            }
            const __bf16* vgb = vf_ + ((size_t)(b * 64 + kt) * 16) * 512;
#pragma unroll
            for (int h = 0; h < 4; h++) {
                int g = h * 256 + tid;
                GLOAD_LDS16(vgb + (size_t)g * 8,
                            ldsV + (h * 256 + w * 64) * 8);
            }
        }
        __syncthreads();   // (B) vmcnt drained -> K/V visible

        // ---- St = K Q^T  (32 s x 16 q per wave) ----
        f32x4 s[2];
#pragma unroll
        for (int i = 0; i < 2; i++) s[i] = (f32x4){0.f, 0.f, 0.f, 0.f};
#pragma unroll
        for (int ns = 0; ns < 2; ns++)
#pragma unroll
            for (int ks = 0; ks < 8; ks++) {
                bf16x8 kfr = *(const bf16x8*)&ldsK[(ks * 2 + ns) * 512 + lane * 8];
                s[ns] = MFMA16(kfr, qf[ks], s[ns]);
            }
        // ---- causal mask ----
        if (kt * 32 + 31 > wrow) {
#pragma unroll
            for (int ns = 0; ns < 2; ns++)
#pragma unroll
                for (int i = 0; i < 4; i++)
                    if (kt * 32 + ns * 16 + quad * 4 + i > qglob)
                        s[ns][i] = -__builtin_inff();
        }
        // ---- online softmax: per-lane + 2 shfl steps ----
        float pm = -__builtin_inff();
#pragma unroll
        for (int ns = 0; ns < 2; ns++)
#pragma unroll
            for (int i = 0; i < 4; i++) pm = fmaxf(pm, s[ns][i]);
        pm = fmaxf(pm, __shfl_xor(pm, 16));
        pm = fmaxf(pm, __shfl_xor(pm, 32));

        float mn = fmaxf(mi, pm);
        float al = exp2f(mi - mn);
        mi = mn;
        float p[2][4], rs = 0.f;
#pragma unroll
        for (int ns = 0; ns < 2; ns++)
#pragma unroll
            for (int i = 0; i < 4; i++) {
                p[ns][i] = exp2f(s[ns][i] - mn);
                rs += p[ns][i];
            }
        rs += __shfl_xor(rs, 16);
        rs += __shfl_xor(rs, 32);
        li = li * al + rs;

        // ---- rescale accO: per-lane multiply (q = cm matches softmax lane)
        if (__any(al != 1.0f)) {
#pragma unroll
            for (int nt = 0; nt < 16; nt++)
#pragma unroll
                for (int i = 0; i < 4; i++) accO[nt][i] *= al;
        }

        // ---- P -> private per-wave LDS in PV operand layout ----
#pragma unroll
        for (int ns = 0; ns < 2; ns++)
#pragma unroll
            for (int i2 = 0; i2 < 2; i2++) {
                bf16x2 d2;
                d2[0] = (__bf16)p[ns][2 * i2];
                d2[1] = (__bf16)p[ns][2 * i2 + 1];
                int off = ((ns * 2 + (quad >> 1)) * 16 + cm) * 8
                          + (quad & 1) * 4 + i2 * 2;
                *(bf16x2*)&ldsP[w][off] = d2;
            }
        // ---- O += V^T-frag x P-frag  (A = V: m=d, k=s; B = P: n=q, k=s) ----
        bf16x8 pfrag = *(const bf16x8*)&ldsP[w][(quad * 16 + cm) * 8];
#pragma unroll
        for (int nt = 0; nt < 16; nt++) {
            bf16x8 vfr = *(const bf16x8*)&ldsV[(nt * 64 + lane) * 8];
            accO[nt] = MFMA16(vfr, pfrag, accO[nt]);
        }
    }

    // ---- epilogue: coalesced bf16x4 stores + fp32 (m, l) ----
    // accO[nt][i]: d = nt*16 + quad*4 + i, q-row = w*16 + cm
    __bf16* op = Opart + ((size_t)lpid * 64 + w * 16 + cm) * HS_;
#pragma unroll
    for (int nt = 0; nt < 16; nt++) {
        bf16x4 v4;
        v4[0] = (__bf16)accO[nt][0]; v4[1] = (__bf16)accO[nt][1];
        v4[2] = (__bf16)accO[nt][2]; v4[3] = (__bf16)accO[nt][3];
        *(bf16x4*)(op + nt * 16 + quad * 4) = v4;
    }
    if (quad == 0) {
        mpart[lpid * 64 + w * 16 + cm] = mi;
        lpart[lpid * 64 + w * 16 + cm] = li;
    }
}

// ---------------------------------------------------------------------------
// Kernel 3b: combine partials.  Grid (256, 4): block = (b, qb) x 16 rows.
// ---------------------------------------------------------------------------
__global__ __launch_bounds__(256) void flash_combine(const __bf16* __restrict__ Opart,
                                                     const float* __restrict__ mpart,
                                                     const float* __restrict__ lpart,
                                                     float* __restrict__ out) {
    const int b    = blockIdx.x >> 5;
    const int qb   = blockIdx.x & 31;
    const int nc   = (qb >> 2) + 1;
    const int pid0 = b * CHUNKS_PER_BATCH + chunk_cum64(qb);

    const int tid  = threadIdx.x;
    const int col  = (tid & 63) * 4;
    const int r0   = blockIdx.y * 16 + (tid >> 6) * 4;

    f32x4 ms = (f32x4){-__builtin_inff(), -__builtin_inff(),
                       -__builtin_inff(), -__builtin_inff()};
    for (int c = 0; c < nc; c++) {
        f32x4 m4 = *(const f32x4*)(mpart + (pid0 + c) * 64 + r0);
#pragma unroll
        for (int i = 0; i < 4; i++) ms[i] = fmaxf(ms[i], m4[i]);
    }
    f32x4 acc[4];
#pragma unroll
    for (int i = 0; i < 4; i++) acc[i] = (f32x4){0.f, 0.f, 0.f, 0.f};
    f32x4 lt = (f32x4){0.f, 0.f, 0.f, 0.f};
    for (int c = 0; c < nc; c++) {
        f32x4 m4 = *(const f32x4*)(mpart + (pid0 + c) * 64 + r0);
        f32x4 l4 = *(const f32x4*)(lpart + (pid0 + c) * 64 + r0);
#pragma unroll
        for (int i = 0; i < 4; i++) {
            float sc = exp2f(m4[i] - ms[i]);
            lt[i] += l4[i] * sc;
            bf16x4 o = *(const bf16x4*)(Opart
                        + ((size_t)(pid0 + c) * 64 + r0 + i) * HS_ + col);
            acc[i][0] += (float)o[0] * sc; acc[i][1] += (float)o[1] * sc;
            acc[i][2] += (float)o[2] * sc; acc[i][3] += (float)o[3] * sc;
        }
    }
#pragma unroll
    for (int i = 0; i < 4; i++) {
        float inv = 1.0f / lt[i];
        f32x4 res = (f32x4){acc[i][0] * inv, acc[i][1] * inv,
                            acc[i][2] * inv, acc[i][3] * inv};
        *(f32x4*)(out + ((size_t)(b * T_ + qb * 64 + r0 + i)) * HS_ + col) = res;
    }
}

// ---------------------------------------------------------------------------
extern "C" void kernel_launch(void* const* d_in, const int* in_sizes, int n_in,
                              void* d_out, int out_size, void* d_ws, size_t ws_size,
                              hipStream_t stream) {
    const float* x  = (const float*)d_in[0];
    const float* Wq = (const float*)d_in[1];
    const float* Wk = (const float*)d_in[2];
    const float* Wv = (const float*)d_in[3];
    float* out = (float*)d_out;

    char* ws = (char*)d_ws;
    size_t off = 0;
    __bf16* wt_all = (__bf16*)(ws + off); off += 1179648;
    __bf16* qfrag  = (__bf16*)(ws + off); off += 8388608;
    __bf16* kfrag  = (__bf16*)(ws + off); off += 8388608;
    __bf16* vfrag  = (__bf16*)(ws + off); off += 8388608;
    __bf16* xb     = (__bf16*)(ws + off);              // union with Opart
    __bf16* Opart  = (__bf16*)(ws + off); off += (size_t)NSLOT * 64 * HS_ * 2;
    float*  mpart  = (float*)(ws + off);  off += (size_t)NSLOT * 64 * 4;
    float*  lpart  = (float*)(ws + off);

    float qscale = 1.4426950408889634f / sqrtf((float)C_);

    prep_kernel<<<dim3(6432), 256, 0, stream>>>(x, Wq, Wk, Wv, xb, wt_all, qscale);
    proj_kernel<<<dim3(128, 6), 256, 0, stream>>>(xb, wt_all, qfrag, kfrag, vfrag);
    flash_part<<<dim3(NSLOT), 256, 0, stream>>>(qfrag, kfrag, vfrag, Opart, mpart, lpart);
    flash_combine<<<dim3(256, 4), 256, 0, stream>>>(Opart, mpart, lpart, out);
}

// Round 11
// 180.910 us; speedup vs baseline: 1.3403x; 1.0612x over previous
//
#include <hip/hip_runtime.h>
#include <hip/hip_bf16.h>
#include <math.h>

// Problem constants
#define B_  8
#define T_  2048
#define C_  768
#define HS_ 256

// Split-K flash: q-block = 64 rows, k-tile = 32 keys, chunk = 8 k-tiles
// (256 keys). q-block qb (0..31) has 2qb+2 k-tiles; chunks(qb) = (qb>>2)+1;
// per-batch chunk total = 144; blocks = 8 * 144 = 1152.
#define CHUNKS_PER_BATCH 144
#define NSLOT (CHUNKS_PER_BATCH * B_)   // 1152

typedef float  f32x4  __attribute__((ext_vector_type(4)));
typedef __bf16 bf16x8 __attribute__((ext_vector_type(8)));
typedef __bf16 bf16x4 __attribute__((ext_vector_type(4)));
typedef __bf16 bf16x2 __attribute__((ext_vector_type(2)));

#define MFMA16(a, b, c) __builtin_amdgcn_mfma_f32_16x16x32_bf16((a), (b), (c), 0, 0, 0)

// global->LDS async copy, 16B per lane (dest = wave-uniform base + lane*16)
#define GLOAD_LDS16(gp, lp)                                                     \
    __builtin_amdgcn_global_load_lds(                                           \
        (const __attribute__((address_space(1))) void*)(gp),                    \
        (__attribute__((address_space(3))) void*)(lp), 16, 0, 0)

// cumulative chunk count before q-block qb: g=qb>>2 -> 2g(g+1) + (qb&3)(g+1)
__device__ __forceinline__ int chunk_cum64(int qb) {
    int g = qb >> 2;
    return 2 * g * (g + 1) + (qb & 3) * (g + 1);
}

// ---------------------------------------------------------------------------
// Kernel 0: prep = x cast (blocks 0..6143) + weight transpose (6144..6431).
// ---------------------------------------------------------------------------
__global__ __launch_bounds__(256) void prep_kernel(const float* __restrict__ x,
                                                   const float* __restrict__ Wq,
                                                   const float* __restrict__ Wk,
                                                   const float* __restrict__ Wv,
                                                   __bf16* __restrict__ xb,
                                                   __bf16* __restrict__ wt_all,
                                                   float qscale) {
    const int bid = blockIdx.x;
    if (bid < 6144) {
        size_t i = ((size_t)bid * 256 + threadIdx.x) * 8;
        f32x4 a = *(const f32x4*)(x + i);
        f32x4 b = *(const f32x4*)(x + i + 4);
        bf16x8 o;
        o[0] = (__bf16)a[0]; o[1] = (__bf16)a[1]; o[2] = (__bf16)a[2]; o[3] = (__bf16)a[3];
        o[4] = (__bf16)b[0]; o[5] = (__bf16)b[1]; o[6] = (__bf16)b[2]; o[7] = (__bf16)b[3];
        *(bf16x8*)(xb + i) = o;
    } else {
        int idx = (bid - 6144) * 256 + threadIdx.x;   // [0, 73728)
        int n   = idx & 255;
        int t   = idx >> 8;          // [0, 288) = mat*96 + k8
        int mat = t / 96;
        int k8  = t - mat * 96;
        const float* W = (mat == 0) ? Wq : ((mat == 1) ? Wk : Wv);
        float scale = (mat == 0) ? qscale : 1.0f;
        bf16x8 o;
#pragma unroll
        for (int j = 0; j < 8; j++)
            o[j] = (__bf16)(W[(k8 * 8 + j) * HS_ + n] * scale);
        *(bf16x8*)&wt_all[((size_t)mat * HS_ + n) * C_ + k8 * 8] = o;
    }
}

// ---------------------------------------------------------------------------
// Kernel 2: fused QKV GEMM. BK=32, double-buffered LDS, one barrier/iter.
//   Q/K tiles: swapped operands (C rows carry d) -> coalesced bf16x4 stores.
// Fragment layouts (element index, all *8 = 8 bf16 per lane slot):
//   Q: ((((b*32+qt)*4 + w16)*8 + ks )*64 + lane)   lane&15 = q, quad = (d>>3)&3, j = d&7
//   K: ((((b*32+kt)*8 + ks )*4 + ns )*64 + lane)   lane&15 = s, quad = (d>>3)&3, j = d&7
//   V: ((((b*32+kt)*2 + ks2)*16 + ntv)*64 + lane)  lane&15 = d, quad = (s>>3)&3, j = s&7
// ---------------------------------------------------------------------------
__global__ __launch_bounds__(256) void proj_kernel(const __bf16* __restrict__ xb,
                                                   const __bf16* __restrict__ wt,
                                                   __bf16* __restrict__ qf_,
                                                   __bf16* __restrict__ kf_,
                                                   __bf16* __restrict__ vf_) {
    __shared__ alignas(16) __bf16 ldsA[2][128 * 32];   // 2 x 8 KB
    __shared__ alignas(16) __bf16 ldsB[2][128 * 32];   // 2 x 8 KB

    const int tid  = threadIdx.x;
    const int w    = tid >> 6;
    const int lane = tid & 63;
    const int cm   = lane & 15;
    const int quad = lane >> 4;
    const int wm   = w & 1;
    const int wn   = w >> 1;
    const int m0   = blockIdx.x * 128;
    const int n0   = blockIdx.y * 128;
    const int mat  = n0 >> 8;                 // 0=Q 1=K 2=V

    f32x4 acc[4][4];
#pragma unroll
    for (int i = 0; i < 4; i++)
#pragma unroll
        for (int j = 0; j < 4; j++) acc[i][j] = (f32x4){0.f, 0.f, 0.f, 0.f};

    // prologue: stage k-iter 0 into buffer 0
#pragma unroll
    for (int h = 0; h < 2; h++) {
        int c = tid + h * 256;   // 512 chunks: row = c>>2, col granule = (c&3)*8
        GLOAD_LDS16(xb + (size_t)(m0 + (c >> 2)) * C_ + (c & 3) * 8, &ldsA[0][c * 8]);
        GLOAD_LDS16(wt + (size_t)(n0 + (c >> 2)) * C_ + (c & 3) * 8, &ldsB[0][c * 8]);
    }

    for (int kt = 0; kt < 24; kt++) {
        const int cur = kt & 1;
        __syncthreads();   // drains vmcnt -> buf[cur] staged; prev reads done

        if (kt < 23) {
            const int k0 = (kt + 1) * 32;
#pragma unroll
            for (int h = 0; h < 2; h++) {
                int c = tid + h * 256;
                GLOAD_LDS16(xb + (size_t)(m0 + (c >> 2)) * C_ + k0 + (c & 3) * 8,
                            &ldsA[cur ^ 1][c * 8]);
                GLOAD_LDS16(wt + (size_t)(n0 + (c >> 2)) * C_ + k0 + (c & 3) * 8,
                            &ldsB[cur ^ 1][c * 8]);
            }
        }

        bf16x8 af[4], bfr[4];
#pragma unroll
        for (int mt = 0; mt < 4; mt++)
            af[mt] = *(const bf16x8*)&ldsA[cur][(wm * 64 + mt * 16 + cm) * 32 + quad * 8];
#pragma unroll
        for (int nt = 0; nt < 4; nt++)
            bfr[nt] = *(const bf16x8*)&ldsB[cur][(wn * 64 + nt * 16 + cm) * 32 + quad * 8];
        if (mat < 2) {
#pragma unroll
            for (int dt = 0; dt < 4; dt++)
#pragma unroll
                for (int qt2 = 0; qt2 < 4; qt2++)
                    acc[dt][qt2] = MFMA16(bfr[dt], af[qt2], acc[dt][qt2]);
        } else {
#pragma unroll
            for (int mt = 0; mt < 4; mt++)
#pragma unroll
                for (int nt = 0; nt < 4; nt++)
                    acc[mt][nt] = MFMA16(af[mt], bfr[nt], acc[mt][nt]);
        }
    }

    const int dBase = (n0 & 255) + wn * 64;
    const int b     = m0 >> 11;
    if (mat < 2) {
        const int rt2 = ((m0 & 2047) >> 6) + wm;   // 64-row tile within batch
        __bf16* dst = (mat == 0) ? qf_ : kf_;
#pragma unroll
        for (int dt = 0; dt < 4; dt++)
#pragma unroll
            for (int qt2 = 0; qt2 < 4; qt2++) {
                int d0    = dBase + dt * 16 + quad * 4;   // d of reg i = d0 + i
                int ksq   = d0 >> 5;
                int quadp = (d0 >> 3) & 3;
                int j0    = d0 & 7;
                size_t addr;
                if (mat == 0)
                    addr = ((((size_t)(b * 32 + rt2) * 4 + qt2) * 8 + ksq) * 64
                            + quadp * 16 + cm) * 8 + j0;
                else
                    addr = ((((size_t)(b * 32 + rt2) * 8 + ksq) * 4 + qt2) * 64
                            + quadp * 16 + cm) * 8 + j0;
                bf16x4 v4;
                v4[0] = (__bf16)acc[dt][qt2][0]; v4[1] = (__bf16)acc[dt][qt2][1];
                v4[2] = (__bf16)acc[dt][qt2][2]; v4[3] = (__bf16)acc[dt][qt2][3];
                *(bf16x4*)(dst + addr) = v4;
            }
    } else {
        const int rt = ((m0 & 2047) + wm * 64) >> 6;
#pragma unroll
        for (int mt = 0; mt < 4; mt++) {
            int ks2   = (mt >> 1) & 1;
            int quadF = (mt & 1) * 2 + (quad >> 1);
            int jb    = (quad & 1) * 4;
#pragma unroll
            for (int nt = 0; nt < 4; nt++) {
                int ntv = (dBase >> 4) + nt;
                size_t idx = ((((size_t)(b * 32 + rt) * 2 + ks2) * 16 + ntv) * 64
                              + quadF * 16 + cm) * 8 + jb;
                bf16x4 v4;
                v4[0] = (__bf16)acc[mt][nt][0]; v4[1] = (__bf16)acc[mt][nt][1];
                v4[2] = (__bf16)acc[mt][nt][2]; v4[3] = (__bf16)acc[mt][nt][3];
                *(bf16x4*)(vf_ + idx) = v4;
            }
        }
    }
}

// ---------------------------------------------------------------------------
// Kernel 3a: split-K causal flash partial — FIXED-ANCHOR softmax.
//   m is set from the FIRST tile's max and never updated: no per-tile
//   max-reduce, no alpha, no 64-wide accO rescale; exp2 issues right after
//   the mask. Safe: later exponents stay far below fp32/bf16 range, and
//   combine renormalizes across chunks with exact (m, l).
//   __launch_bounds__(256,3): 3 waves/SIMD target (combined regs ~165<=170).
// ---------------------------------------------------------------------------
__global__ __launch_bounds__(256, 3) void flash_part(const __bf16* __restrict__ qf_,
                                                     const __bf16* __restrict__ kf_,
                                                     const __bf16* __restrict__ vf_,
                                                     __bf16* __restrict__ Opart,
                                                     float* __restrict__ mpart,
                                                     float* __restrict__ lpart) {
    __shared__ alignas(16) __bf16 ldsK[8 * 2 * 64 * 8];   // 16 KB
    __shared__ alignas(16) __bf16 ldsV[16 * 64 * 8];      // 16 KB
    __shared__ alignas(16) __bf16 ldsP[4][512];           // per-wave P (1 KB)

    const int tid  = threadIdx.x;
    const int w    = tid >> 6;       // 0..3
    const int lane = tid & 63;
    const int cm   = lane & 15;      // = q column
    const int quad = lane >> 4;

    const int pid  = blockIdx.x;                // [0, 1152)
    const int b    = pid & 7;                   // batch -> XCD spread
    const int r    = (CHUNKS_PER_BATCH - 1) - (pid >> 3);   // heavy chunks first
    int qb = 0, ci = 0;
    {
        int rr = r;
        for (int j = 0; j < 32; j++) {
            int c = (j >> 2) + 1;
            if (rr < c) { qb = j; ci = rr; break; }
            rr -= c;
        }
    }
    const int lpid = b * CHUNKS_PER_BATCH + r;  // output slot
    const int kt_begin = ci * 8;                        // 32-key tiles
    const int kt_end   = min(kt_begin + 8, 2 * qb + 2);

    // Q fragments (B-operand: lane&15 = q, quad*8+j = d), coalesced loads.
    const __bf16* qp = qf_ + (((size_t)(b * 32 + qb) * 4 + w) * 8) * 512 + lane * 8;
    bf16x8 qf[8];
#pragma unroll
    for (int ks = 0; ks < 8; ks++) qf[ks] = *(const bf16x8*)(qp + ks * 512);

    f32x4 accO[16];   // accO[nt][i]: d = nt*16 + quad*4 + i, q = cm
#pragma unroll
    for (int i = 0; i < 16; i++) accO[i] = (f32x4){0.f, 0.f, 0.f, 0.f};
    float mi = 0.f, li = 0.f;        // mi fixed after first tile

    const int wrow  = qb * 64 + w * 16;
    const int qglob = wrow + cm;

    for (int kt = kt_begin; kt < kt_end; kt++) {
        __syncthreads();   // (A) prior tile's LDS fully consumed

        // ---- stage K (16 KB) + V (16 KB) tile, async ----
        {
            const int kt64 = kt >> 1, kh = kt & 1;
            const __bf16* kgb = kf_ + (((size_t)(b * 32 + kt64) * 8) * 4 + kh * 2) * 512;
#pragma unroll
            for (int h = 0; h < 4; h++) {
                int g = h * 256 + tid;
                int ks = g >> 7, sub = g & 127;
                GLOAD_LDS16(kgb + (size_t)ks * 4 * 512 + sub * 8,
                            ldsK + (h * 256 + w * 64) * 8);
            }
            const __bf16* vgb = vf_ + ((size_t)(b * 64 + kt) * 16) * 512;
#pragma unroll
            for (int h = 0; h < 4; h++) {
                int g = h * 256 + tid;
                GLOAD_LDS16(vgb + (size_t)g * 8,
                            ldsV + (h * 256 + w * 64) * 8);
            }
        }
        __syncthreads();   // (B) vmcnt drained -> K/V visible

        // ---- St = K Q^T  (32 s x 16 q per wave) ----
        f32x4 s[2];
#pragma unroll
        for (int i = 0; i < 2; i++) s[i] = (f32x4){0.f, 0.f, 0.f, 0.f};
#pragma unroll
        for (int ns = 0; ns < 2; ns++)
#pragma unroll
            for (int ks = 0; ks < 8; ks++) {
                bf16x8 kfr = *(const bf16x8*)&ldsK[(ks * 2 + ns) * 512 + lane * 8];
                s[ns] = MFMA16(kfr, qf[ks], s[ns]);
            }
        // ---- causal mask ----
        if (kt * 32 + 31 > wrow) {
#pragma unroll
            for (int ns = 0; ns < 2; ns++)
#pragma unroll
                for (int i = 0; i < 4; i++)
                    if (kt * 32 + ns * 16 + quad * 4 + i > qglob)
                        s[ns][i] = -__builtin_inff();
        }
        // ---- fixed-anchor softmax: establish m once (first tile) ----
        if (kt == kt_begin) {
            float pm = -__builtin_inff();
#pragma unroll
            for (int ns = 0; ns < 2; ns++)
#pragma unroll
                for (int i = 0; i < 4; i++) pm = fmaxf(pm, s[ns][i]);
            pm = fmaxf(pm, __shfl_xor(pm, 16));
            pm = fmaxf(pm, __shfl_xor(pm, 32));
            mi = pm;
        }
        float p[2][4], rs = 0.f;
#pragma unroll
        for (int ns = 0; ns < 2; ns++)
#pragma unroll
            for (int i = 0; i < 4; i++) {
                p[ns][i] = exp2f(s[ns][i] - mi);
                rs += p[ns][i];
            }
        rs += __shfl_xor(rs, 16);
        rs += __shfl_xor(rs, 32);
        li += rs;

        // ---- P -> private per-wave LDS in PV operand layout ----
#pragma unroll
        for (int ns = 0; ns < 2; ns++)
#pragma unroll
            for (int i2 = 0; i2 < 2; i2++) {
                bf16x2 d2;
                d2[0] = (__bf16)p[ns][2 * i2];
                d2[1] = (__bf16)p[ns][2 * i2 + 1];
                int off = ((ns * 2 + (quad >> 1)) * 16 + cm) * 8
                          + (quad & 1) * 4 + i2 * 2;
                *(bf16x2*)&ldsP[w][off] = d2;
            }
        // ---- O += V^T-frag x P-frag ----
        bf16x8 pfrag = *(const bf16x8*)&ldsP[w][(quad * 16 + cm) * 8];
#pragma unroll
        for (int nt = 0; nt < 16; nt++) {
            bf16x8 vfr = *(const bf16x8*)&ldsV[(nt * 64 + lane) * 8];
            accO[nt] = MFMA16(vfr, pfrag, accO[nt]);
        }
    }

    // ---- epilogue: coalesced bf16x4 stores + fp32 (m, l) ----
    __bf16* op = Opart + ((size_t)lpid * 64 + w * 16 + cm) * HS_;
#pragma unroll
    for (int nt = 0; nt < 16; nt++) {
        bf16x4 v4;
        v4[0] = (__bf16)accO[nt][0]; v4[1] = (__bf16)accO[nt][1];
        v4[2] = (__bf16)accO[nt][2]; v4[3] = (__bf16)accO[nt][3];
        *(bf16x4*)(op + nt * 16 + quad * 4) = v4;
    }
    if (quad == 0) {
        mpart[lpid * 64 + w * 16 + cm] = mi;
        lpart[lpid * 64 + w * 16 + cm] = li;
    }
}

// ---------------------------------------------------------------------------
// Kernel 3b: combine partials.  Grid (256, 4): block = (b, qb) x 16 rows.
// ---------------------------------------------------------------------------
__global__ __launch_bounds__(256) void flash_combine(const __bf16* __restrict__ Opart,
                                                     const float* __restrict__ mpart,
                                                     const float* __restrict__ lpart,
                                                     float* __restrict__ out) {
    const int b    = blockIdx.x >> 5;
    const int qb   = blockIdx.x & 31;
    const int nc   = (qb >> 2) + 1;
    const int pid0 = b * CHUNKS_PER_BATCH + chunk_cum64(qb);

    const int tid  = threadIdx.x;
    const int col  = (tid & 63) * 4;
    const int r0   = blockIdx.y * 16 + (tid >> 6) * 4;

    f32x4 ms = (f32x4){-__builtin_inff(), -__builtin_inff(),
                       -__builtin_inff(), -__builtin_inff()};
    for (int c = 0; c < nc; c++) {
        f32x4 m4 = *(const f32x4*)(mpart + (pid0 + c) * 64 + r0);
#pragma unroll
        for (int i = 0; i < 4; i++) ms[i] = fmaxf(ms[i], m4[i]);
    }
    f32x4 acc[4];
#pragma unroll
    for (int i = 0; i < 4; i++) acc[i] = (f32x4){0.f, 0.f, 0.f, 0.f};
    f32x4 lt = (f32x4){0.f, 0.f, 0.f, 0.f};
    for (int c = 0; c < nc; c++) {
        f32x4 m4 = *(const f32x4*)(mpart + (pid0 + c) * 64 + r0);
        f32x4 l4 = *(const f32x4*)(lpart + (pid0 + c) * 64 + r0);
#pragma unroll
        for (int i = 0; i < 4; i++) {
            float sc = exp2f(m4[i] - ms[i]);
            lt[i] += l4[i] * sc;
            bf16x4 o = *(const bf16x4*)(Opart
                        + ((size_t)(pid0 + c) * 64 + r0 + i) * HS_ + col);
            acc[i][0] += (float)o[0] * sc; acc[i][1] += (float)o[1] * sc;
            acc[i][2] += (float)o[2] * sc; acc[i][3] += (float)o[3] * sc;
        }
    }
#pragma unroll
    for (int i = 0; i < 4; i++) {
        float inv = 1.0f / lt[i];
        f32x4 res = (f32x4){acc[i][0] * inv, acc[i][1] * inv,
                            acc[i][2] * inv, acc[i][3] * inv};
        *(f32x4*)(out + ((size_t)(b * T_ + qb * 64 + r0 + i)) * HS_ + col) = res;
    }
}

// ---------------------------------------------------------------------------
extern "C" void kernel_launch(void* const* d_in, const int* in_sizes, int n_in,
                              void* d_out, int out_size, void* d_ws, size_t ws_size,
                              hipStream_t stream) {
    const float* x  = (const float*)d_in[0];
    const float* Wq = (const float*)d_in[1];
    const float* Wk = (const float*)d_in[2];
    const float* Wv = (const float*)d_in[3];
    float* out = (float*)d_out;

    char* ws = (char*)d_ws;
    size_t off = 0;
    __bf16* wt_all = (__bf16*)(ws + off); off += 1179648;
    __bf16* qfrag  = (__bf16*)(ws + off); off += 8388608;
    __bf16* kfrag  = (__bf16*)(ws + off); off += 8388608;
    __bf16* vfrag  = (__bf16*)(ws + off); off += 8388608;
    __bf16* xb     = (__bf16*)(ws + off);              // union with Opart
    __bf16* Opart  = (__bf16*)(ws + off); off += (size_t)NSLOT * 64 * HS_ * 2;
    float*  mpart  = (float*)(ws + off);  off += (size_t)NSLOT * 64 * 4;
    float*  lpart  = (float*)(ws + off);

    float qscale = 1.4426950408889634f / sqrtf((float)C_);

    prep_kernel<<<dim3(6432), 256, 0, stream>>>(x, Wq, Wk, Wv, xb, wt_all, qscale);
    proj_kernel<<<dim3(128, 6), 256, 0, stream>>>(xb, wt_all, qfrag, kfrag, vfrag);
    flash_part<<<dim3(NSLOT), 256, 0, stream>>>(qfrag, kfrag, vfrag, Opart, mpart, lpart);
    flash_combine<<<dim3(256, 4), 256, 0, stream>>>(Opart, mpart, lpart, out);
}

// Round 12
// 180.493 us; speedup vs baseline: 1.3433x; 1.0023x over previous
//
#include <hip/hip_runtime.h>
#include <hip/hip_bf16.h>
#include <math.h>

// Problem constants
#define B_  8
#define T_  2048
#define C_  768
#define HS_ 256

// Split-K flash: q-block = 64 rows, k-tile = 64 keys, chunk = 8 k-tiles
// (512 keys). q-block qb (0..31) has qb+1 k-tiles; chunks(qb) = (qb>>3)+1;
// per-batch chunk total = 80; blocks = 8 * 80 = 640.
#define CHUNKS_PER_BATCH 80
#define NSLOT (CHUNKS_PER_BATCH * B_)   // 640

typedef float  f32x4  __attribute__((ext_vector_type(4)));
typedef __bf16 bf16x8 __attribute__((ext_vector_type(8)));
typedef __bf16 bf16x4 __attribute__((ext_vector_type(4)));
typedef __bf16 bf16x2 __attribute__((ext_vector_type(2)));

#define MFMA16(a, b, c) __builtin_amdgcn_mfma_f32_16x16x32_bf16((a), (b), (c), 0, 0, 0)

// global->LDS async copy, 16B per lane (dest = wave-uniform base + lane*16)
#define GLOAD_LDS16(gp, lp)                                                     \
    __builtin_amdgcn_global_load_lds(                                           \
        (const __attribute__((address_space(1))) void*)(gp),                    \
        (__attribute__((address_space(3))) void*)(lp), 16, 0, 0)

// cumulative chunk count before q-block qb: g=qb>>3 -> 4g(g+1) + (qb&7)(g+1)
__device__ __forceinline__ int chunk_cum64(int qb) {
    int g = qb >> 3;
    return 4 * g * (g + 1) + (qb & 7) * (g + 1);
}

// ---------------------------------------------------------------------------
// Kernel 0: prep = x cast (blocks 0..6143) + weight transpose (6144..6431).
// ---------------------------------------------------------------------------
__global__ __launch_bounds__(256) void prep_kernel(const float* __restrict__ x,
                                                   const float* __restrict__ Wq,
                                                   const float* __restrict__ Wk,
                                                   const float* __restrict__ Wv,
                                                   __bf16* __restrict__ xb,
                                                   __bf16* __restrict__ wt_all,
                                                   float qscale) {
    const int bid = blockIdx.x;
    if (bid < 6144) {
        size_t i = ((size_t)bid * 256 + threadIdx.x) * 8;
        f32x4 a = *(const f32x4*)(x + i);
        f32x4 b = *(const f32x4*)(x + i + 4);
        bf16x8 o;
        o[0] = (__bf16)a[0]; o[1] = (__bf16)a[1]; o[2] = (__bf16)a[2]; o[3] = (__bf16)a[3];
        o[4] = (__bf16)b[0]; o[5] = (__bf16)b[1]; o[6] = (__bf16)b[2]; o[7] = (__bf16)b[3];
        *(bf16x8*)(xb + i) = o;
    } else {
        int idx = (bid - 6144) * 256 + threadIdx.x;   // [0, 73728)
        int n   = idx & 255;
        int t   = idx >> 8;          // [0, 288) = mat*96 + k8
        int mat = t / 96;
        int k8  = t - mat * 96;
        const float* W = (mat == 0) ? Wq : ((mat == 1) ? Wk : Wv);
        float scale = (mat == 0) ? qscale : 1.0f;
        bf16x8 o;
#pragma unroll
        for (int j = 0; j < 8; j++)
            o[j] = (__bf16)(W[(k8 * 8 + j) * HS_ + n] * scale);
        *(bf16x8*)&wt_all[((size_t)mat * HS_ + n) * C_ + k8 * 8] = o;
    }
}

// ---------------------------------------------------------------------------
// Kernel 2: fused QKV GEMM. BK=32, double-buffered LDS, one barrier/iter.
//   Q/K tiles: swapped operands (C rows carry d) -> coalesced bf16x4 stores.
// Fragment layouts (element index, all *8 = 8 bf16 per lane slot):
//   Q: ((((b*32+qt)*4 + w16)*8 + ks )*64 + lane)   lane&15 = q, quad = (d>>3)&3, j = d&7
//   K: ((((b*32+kt)*8 + ks )*4 + ns )*64 + lane)   lane&15 = s, quad = (d>>3)&3, j = d&7
//   V: ((((b*32+kt)*2 + ks2)*16 + ntv)*64 + lane)  lane&15 = d, quad = (s>>3)&3, j = s&7
// ---------------------------------------------------------------------------
__global__ __launch_bounds__(256) void proj_kernel(const __bf16* __restrict__ xb,
                                                   const __bf16* __restrict__ wt,
                                                   __bf16* __restrict__ qf_,
                                                   __bf16* __restrict__ kf_,
                                                   __bf16* __restrict__ vf_) {
    __shared__ alignas(16) __bf16 ldsA[2][128 * 32];   // 2 x 8 KB
    __shared__ alignas(16) __bf16 ldsB[2][128 * 32];   // 2 x 8 KB

    const int tid  = threadIdx.x;
    const int w    = tid >> 6;
    const int lane = tid & 63;
    const int cm   = lane & 15;
    const int quad = lane >> 4;
    const int wm   = w & 1;
    const int wn   = w >> 1;
    const int m0   = blockIdx.x * 128;
    const int n0   = blockIdx.y * 128;
    const int mat  = n0 >> 8;                 // 0=Q 1=K 2=V

    f32x4 acc[4][4];
#pragma unroll
    for (int i = 0; i < 4; i++)
#pragma unroll
        for (int j = 0; j < 4; j++) acc[i][j] = (f32x4){0.f, 0.f, 0.f, 0.f};

    // prologue: stage k-iter 0 into buffer 0
#pragma unroll
    for (int h = 0; h < 2; h++) {
        int c = tid + h * 256;   // 512 chunks: row = c>>2, col granule = (c&3)*8
        GLOAD_LDS16(xb + (size_t)(m0 + (c >> 2)) * C_ + (c & 3) * 8, &ldsA[0][c * 8]);
        GLOAD_LDS16(wt + (size_t)(n0 + (c >> 2)) * C_ + (c & 3) * 8, &ldsB[0][c * 8]);
    }

    for (int kt = 0; kt < 24; kt++) {
        const int cur = kt & 1;
        __syncthreads();   // drains vmcnt -> buf[cur] staged; prev reads done

        if (kt < 23) {
            const int k0 = (kt + 1) * 32;
#pragma unroll
            for (int h = 0; h < 2; h++) {
                int c = tid + h * 256;
                GLOAD_LDS16(xb + (size_t)(m0 + (c >> 2)) * C_ + k0 + (c & 3) * 8,
                            &ldsA[cur ^ 1][c * 8]);
                GLOAD_LDS16(wt + (size_t)(n0 + (c >> 2)) * C_ + k0 + (c & 3) * 8,
                            &ldsB[cur ^ 1][c * 8]);
            }
        }

        bf16x8 af[4], bfr[4];
#pragma unroll
        for (int mt = 0; mt < 4; mt++)
            af[mt] = *(const bf16x8*)&ldsA[cur][(wm * 64 + mt * 16 + cm) * 32 + quad * 8];
#pragma unroll
        for (int nt = 0; nt < 4; nt++)
            bfr[nt] = *(const bf16x8*)&ldsB[cur][(wn * 64 + nt * 16 + cm) * 32 + quad * 8];
        if (mat < 2) {
#pragma unroll
            for (int dt = 0; dt < 4; dt++)
#pragma unroll
                for (int qt2 = 0; qt2 < 4; qt2++)
                    acc[dt][qt2] = MFMA16(bfr[dt], af[qt2], acc[dt][qt2]);
        } else {
#pragma unroll
            for (int mt = 0; mt < 4; mt++)
#pragma unroll
                for (int nt = 0; nt < 4; nt++)
                    acc[mt][nt] = MFMA16(af[mt], bfr[nt], acc[mt][nt]);
        }
    }

    const int dBase = (n0 & 255) + wn * 64;
    const int b     = m0 >> 11;
    if (mat < 2) {
        const int rt2 = ((m0 & 2047) >> 6) + wm;   // 64-row tile within batch
        __bf16* dst = (mat == 0) ? qf_ : kf_;
#pragma unroll
        for (int dt = 0; dt < 4; dt++)
#pragma unroll
            for (int qt2 = 0; qt2 < 4; qt2++) {
                int d0    = dBase + dt * 16 + quad * 4;   // d of reg i = d0 + i
                int ksq   = d0 >> 5;
                int quadp = (d0 >> 3) & 3;
                int j0    = d0 & 7;
                size_t addr;
                if (mat == 0)
                    addr = ((((size_t)(b * 32 + rt2) * 4 + qt2) * 8 + ksq) * 64
                            + quadp * 16 + cm) * 8 + j0;
                else
                    addr = ((((size_t)(b * 32 + rt2) * 8 + ksq) * 4 + qt2) * 64
                            + quadp * 16 + cm) * 8 + j0;
                bf16x4 v4;
                v4[0] = (__bf16)acc[dt][qt2][0]; v4[1] = (__bf16)acc[dt][qt2][1];
                v4[2] = (__bf16)acc[dt][qt2][2]; v4[3] = (__bf16)acc[dt][qt2][3];
                *(bf16x4*)(dst + addr) = v4;
            }
    } else {
        const int rt = ((m0 & 2047) + wm * 64) >> 6;
#pragma unroll
        for (int mt = 0; mt < 4; mt++) {
            int ks2   = (mt >> 1) & 1;
            int quadF = (mt & 1) * 2 + (quad >> 1);
            int jb    = (quad & 1) * 4;
#pragma unroll
            for (int nt = 0; nt < 4; nt++) {
                int ntv = (dBase >> 4) + nt;
                size_t idx = ((((size_t)(b * 32 + rt) * 2 + ks2) * 16 + ntv) * 64
                              + quadF * 16 + cm) * 8 + jb;
                bf16x4 v4;
                v4[0] = (__bf16)acc[mt][nt][0]; v4[1] = (__bf16)acc[mt][nt][1];
                v4[2] = (__bf16)acc[mt][nt][2]; v4[3] = (__bf16)acc[mt][nt][3];
                *(bf16x4*)(vf_ + idx) = v4;
            }
        }
    }
}

// ---------------------------------------------------------------------------
// Kernel 3a: split-K causal flash partial — 64-key tiles, fixed-anchor
//   softmax. One barrier pair per 64 keys (was per 32): K 32 KB + V 32 KB
//   staged per round (contiguous proj-tile granularity). Per-lane softmax
//   (q = cm), no rescale. P = 2 KB per wave, private (no extra barrier).
// ---------------------------------------------------------------------------
__global__ __launch_bounds__(256, 3) void flash_part(const __bf16* __restrict__ qf_,
                                                     const __bf16* __restrict__ kf_,
                                                     const __bf16* __restrict__ vf_,
                                                     __bf16* __restrict__ Opart,
                                                     float* __restrict__ mpart,
                                                     float* __restrict__ lpart) {
    __shared__ alignas(16) __bf16 ldsK[8 * 4 * 64 * 8];   // [ks8][ns4][lane]x8 = 32 KB
    __shared__ alignas(16) __bf16 ldsV[2 * 16 * 64 * 8];  // [ks2][ntv16][lane]x8 = 32 KB
    __shared__ alignas(16) __bf16 ldsP[4][1024];          // per-wave P (2 KB)

    const int tid  = threadIdx.x;
    const int w    = tid >> 6;       // 0..3
    const int lane = tid & 63;
    const int cm   = lane & 15;      // = q column
    const int quad = lane >> 4;

    const int pid  = blockIdx.x;                // [0, 640)
    const int b    = pid & 7;                   // batch -> XCD spread
    const int r    = (CHUNKS_PER_BATCH - 1) - (pid >> 3);   // heavy chunks first
    int qb = 0, ci = 0;
    {
        int rr = r;
        for (int j = 0; j < 32; j++) {
            int c = (j >> 3) + 1;
            if (rr < c) { qb = j; ci = rr; break; }
            rr -= c;
        }
    }
    const int lpid = b * CHUNKS_PER_BATCH + r;  // output slot
    const int kt_begin = ci * 8;                        // 64-key tiles
    const int kt_end   = min(kt_begin + 8, qb + 1);

    // Q fragments (B-operand: lane&15 = q, quad*8+j = d), coalesced loads.
    const __bf16* qp = qf_ + (((size_t)(b * 32 + qb) * 4 + w) * 8) * 512 + lane * 8;
    bf16x8 qf[8];
#pragma unroll
    for (int ks = 0; ks < 8; ks++) qf[ks] = *(const bf16x8*)(qp + ks * 512);

    f32x4 accO[16];   // accO[nt][i]: d = nt*16 + quad*4 + i, q = cm
#pragma unroll
    for (int i = 0; i < 16; i++) accO[i] = (f32x4){0.f, 0.f, 0.f, 0.f};
    float mi = 0.f, li = 0.f;        // mi fixed after first tile

    const int wrow  = qb * 64 + w * 16;
    const int qglob = wrow + cm;

    for (int kt = kt_begin; kt < kt_end; kt++) {
        __syncthreads();   // (A) prior tile's LDS fully consumed

        // ---- stage K (32 KB) + V (32 KB) tile, async, contiguous ----
        {
            const __bf16* kgb = kf_ + ((size_t)(b * 32 + kt)) * 16384;
            const __bf16* vgb = vf_ + ((size_t)(b * 32 + kt)) * 16384;
#pragma unroll
            for (int h = 0; h < 8; h++) {
                int g = h * 256 + tid;           // 16B slot id, 0..2047
                GLOAD_LDS16(kgb + (size_t)g * 8, ldsK + (h * 256 + w * 64) * 8);
                GLOAD_LDS16(vgb + (size_t)g * 8, ldsV + (h * 256 + w * 64) * 8);
            }
        }
        __syncthreads();   // (B) vmcnt drained -> K/V visible

        // ---- St = K Q^T  (64 s x 16 q per wave) ----
        f32x4 s[4];
#pragma unroll
        for (int i = 0; i < 4; i++) s[i] = (f32x4){0.f, 0.f, 0.f, 0.f};
#pragma unroll
        for (int ns = 0; ns < 4; ns++)
#pragma unroll
            for (int ks = 0; ks < 8; ks++) {
                bf16x8 kfr = *(const bf16x8*)&ldsK[(ks * 4 + ns) * 512 + lane * 8];
                s[ns] = MFMA16(kfr, qf[ks], s[ns]);
            }
        // ---- causal mask (s = kt*64 + ns*16 + quad*4 + i; col q = qglob) ----
        if (kt * 64 + 63 > wrow) {
#pragma unroll
            for (int ns = 0; ns < 4; ns++)
#pragma unroll
                for (int i = 0; i < 4; i++)
                    if (kt * 64 + ns * 16 + quad * 4 + i > qglob)
                        s[ns][i] = -__builtin_inff();
        }
        // ---- fixed-anchor softmax: establish m once (first tile) ----
        if (kt == kt_begin) {
            float pm = -__builtin_inff();
#pragma unroll
            for (int ns = 0; ns < 4; ns++)
#pragma unroll
                for (int i = 0; i < 4; i++) pm = fmaxf(pm, s[ns][i]);
            pm = fmaxf(pm, __shfl_xor(pm, 16));
            pm = fmaxf(pm, __shfl_xor(pm, 32));
            mi = pm;
        }
        float p[4][4], rs = 0.f;
#pragma unroll
        for (int ns = 0; ns < 4; ns++)
#pragma unroll
            for (int i = 0; i < 4; i++) {
                p[ns][i] = exp2f(s[ns][i] - mi);
                rs += p[ns][i];
            }
        rs += __shfl_xor(rs, 16);
        rs += __shfl_xor(rs, 32);
        li += rs;

        // ---- P -> private per-wave LDS in PV B-operand layout ----
        // element (q=cm, s): offset = ((s>>3)*16 + q)*8 + (s&7)
#pragma unroll
        for (int ns = 0; ns < 4; ns++)
#pragma unroll
            for (int i2 = 0; i2 < 2; i2++) {
                bf16x2 d2;
                d2[0] = (__bf16)p[ns][2 * i2];
                d2[1] = (__bf16)p[ns][2 * i2 + 1];
                int off = ((ns * 2 + (quad >> 1)) * 16 + cm) * 8
                          + (quad & 1) * 4 + i2 * 2;
                *(bf16x2*)&ldsP[w][off] = d2;
            }
        // ---- O += V^T-frag x P-frag over 2 s-halves ----
#pragma unroll
        for (int ks2 = 0; ks2 < 2; ks2++) {
            bf16x8 pfrag = *(const bf16x8*)&ldsP[w][((ks2 * 4 + quad) * 16 + cm) * 8];
#pragma unroll
            for (int nt = 0; nt < 16; nt++) {
                bf16x8 vfr = *(const bf16x8*)&ldsV[(ks2 * 16 + nt) * 512 + lane * 8];
                accO[nt] = MFMA16(vfr, pfrag, accO[nt]);
            }
        }
    }

    // ---- epilogue: coalesced bf16x4 stores + fp32 (m, l) ----
    __bf16* op = Opart + ((size_t)lpid * 64 + w * 16 + cm) * HS_;
#pragma unroll
    for (int nt = 0; nt < 16; nt++) {
        bf16x4 v4;
        v4[0] = (__bf16)accO[nt][0]; v4[1] = (__bf16)accO[nt][1];
        v4[2] = (__bf16)accO[nt][2]; v4[3] = (__bf16)accO[nt][3];
        *(bf16x4*)(op + nt * 16 + quad * 4) = v4;
    }
    if (quad == 0) {
        mpart[lpid * 64 + w * 16 + cm] = mi;
        lpart[lpid * 64 + w * 16 + cm] = li;
    }
}

// ---------------------------------------------------------------------------
// Kernel 3b: combine partials.  Grid (256, 4): block = (b, qb) x 16 rows.
// ---------------------------------------------------------------------------
__global__ __launch_bounds__(256) void flash_combine(const __bf16* __restrict__ Opart,
                                                     const float* __restrict__ mpart,
                                                     const float* __restrict__ lpart,
                                                     float* __restrict__ out) {
    const int b    = blockIdx.x >> 5;
    const int qb   = blockIdx.x & 31;
    const int nc   = (qb >> 3) + 1;
    const int pid0 = b * CHUNKS_PER_BATCH + chunk_cum64(qb);

    const int tid  = threadIdx.x;
    const int col  = (tid & 63) * 4;
    const int r0   = blockIdx.y * 16 + (tid >> 6) * 4;

    f32x4 ms = (f32x4){-__builtin_inff(), -__builtin_inff(),
                       -__builtin_inff(), -__builtin_inff()};
    for (int c = 0; c < nc; c++) {
        f32x4 m4 = *(const f32x4*)(mpart + (pid0 + c) * 64 + r0);
#pragma unroll
        for (int i = 0; i < 4; i++) ms[i] = fmaxf(ms[i], m4[i]);
    }
    f32x4 acc[4];
#pragma unroll
    for (int i = 0; i < 4; i++) acc[i] = (f32x4){0.f, 0.f, 0.f, 0.f};
    f32x4 lt = (f32x4){0.f, 0.f, 0.f, 0.f};
    for (int c = 0; c < nc; c++) {
        f32x4 m4 = *(const f32x4*)(mpart + (pid0 + c) * 64 + r0);
        f32x4 l4 = *(const f32x4*)(lpart + (pid0 + c) * 64 + r0);
#pragma unroll
        for (int i = 0; i < 4; i++) {
            float sc = exp2f(m4[i] - ms[i]);
            lt[i] += l4[i] * sc;
            bf16x4 o = *(const bf16x4*)(Opart
                        + ((size_t)(pid0 + c) * 64 + r0 + i) * HS_ + col);
            acc[i][0] += (float)o[0] * sc; acc[i][1] += (float)o[1] * sc;
            acc[i][2] += (float)o[2] * sc; acc[i][3] += (float)o[3] * sc;
        }
    }
#pragma unroll
    for (int i = 0; i < 4; i++) {
        float inv = 1.0f / lt[i];
        f32x4 res = (f32x4){acc[i][0] * inv, acc[i][1] * inv,
                            acc[i][2] * inv, acc[i][3] * inv};
        *(f32x4*)(out + ((size_t)(b * T_ + qb * 64 + r0 + i)) * HS_ + col) = res;
    }
}

// ---------------------------------------------------------------------------
extern "C" void kernel_launch(void* const* d_in, const int* in_sizes, int n_in,
                              void* d_out, int out_size, void* d_ws, size_t ws_size,
                              hipStream_t stream) {
    const float* x  = (const float*)d_in[0];
    const float* Wq = (const float*)d_in[1];
    const float* Wk = (const float*)d_in[2];
    const float* Wv = (const float*)d_in[3];
    float* out = (float*)d_out;

    char* ws = (char*)d_ws;
    // ws: wt 1.18 MB | q/k/v frags 3 x 8.39 MB | union{ xb 25.2 MB ,
    //     Opart(bf16) 21 MB + mpart/lpart 0.16 MB x2 }   (xb dead after proj)
    size_t off = 0;
    __bf16* wt_all = (__bf16*)(ws + off); off += 1179648;
    __bf16* qfrag  = (__bf16*)(ws + off); off += 8388608;
    __bf16* kfrag  = (__bf16*)(ws + off); off += 8388608;
    __bf16* vfrag  = (__bf16*)(ws + off); off += 8388608;
    __bf16* xb     = (__bf16*)(ws + off);              // union with Opart
    __bf16* Opart  = (__bf16*)(ws + off); off += (size_t)NSLOT * 64 * HS_ * 2;
    float*  mpart  = (float*)(ws + off);  off += (size_t)NSLOT * 64 * 4;
    float*  lpart  = (float*)(ws + off);

    float qscale = 1.4426950408889634f / sqrtf((float)C_);

    prep_kernel<<<dim3(6432), 256, 0, stream>>>(x, Wq, Wk, Wv, xb, wt_all, qscale);
    proj_kernel<<<dim3(128, 6), 256, 0, stream>>>(xb, wt_all, qfrag, kfrag, vfrag);
    flash_part<<<dim3(NSLOT), 256, 0, stream>>>(qfrag, kfrag, vfrag, Opart, mpart, lpart);
    flash_combine<<<dim3(256, 4), 256, 0, stream>>>(Opart, mpart, lpart, out);
}

// Round 13
// 174.465 us; speedup vs baseline: 1.3898x; 1.0346x over previous
//
#include <hip/hip_runtime.h>
#include <hip/hip_bf16.h>
#include <math.h>

// Problem constants
#define B_  8
#define T_  2048
#define C_  768
#define HS_ 256

// Split-K flash: q-block = 64 rows, k-tile = 32 keys, chunk = 16 k-tiles
// (512 keys). q-block qb (0..31) has 2qb+2 k-tiles; chunks(qb) = (qb>>3)+1;
// per-batch chunk total = 80; blocks = 8 * 80 = 640.
#define CHUNKS_PER_BATCH 80
#define NSLOT (CHUNKS_PER_BATCH * B_)   // 640

typedef float  f32x4  __attribute__((ext_vector_type(4)));
typedef __bf16 bf16x8 __attribute__((ext_vector_type(8)));
typedef __bf16 bf16x4 __attribute__((ext_vector_type(4)));
typedef __bf16 bf16x2 __attribute__((ext_vector_type(2)));

#define MFMA16(a, b, c) __builtin_amdgcn_mfma_f32_16x16x32_bf16((a), (b), (c), 0, 0, 0)

// global->LDS async copy, 16B per lane (dest = wave-uniform base + lane*16)
#define GLOAD_LDS16(gp, lp)                                                     \
    __builtin_amdgcn_global_load_lds(                                           \
        (const __attribute__((address_space(1))) void*)(gp),                    \
        (__attribute__((address_space(3))) void*)(lp), 16, 0, 0)

// cumulative chunk count before q-block qb: g=qb>>3 -> 4g(g+1) + (qb&7)(g+1)
__device__ __forceinline__ int chunk_cum64(int qb) {
    int g = qb >> 3;
    return 4 * g * (g + 1) + (qb & 7) * (g + 1);
}

// ---------------------------------------------------------------------------
// Kernel 0: prep = x cast (blocks 0..6143) + weight transpose (6144..6431).
// ---------------------------------------------------------------------------
__global__ __launch_bounds__(256) void prep_kernel(const float* __restrict__ x,
                                                   const float* __restrict__ Wq,
                                                   const float* __restrict__ Wk,
                                                   const float* __restrict__ Wv,
                                                   __bf16* __restrict__ xb,
                                                   __bf16* __restrict__ wt_all,
                                                   float qscale) {
    const int bid = blockIdx.x;
    if (bid < 6144) {
        size_t i = ((size_t)bid * 256 + threadIdx.x) * 8;
        f32x4 a = *(const f32x4*)(x + i);
        f32x4 b = *(const f32x4*)(x + i + 4);
        bf16x8 o;
        o[0] = (__bf16)a[0]; o[1] = (__bf16)a[1]; o[2] = (__bf16)a[2]; o[3] = (__bf16)a[3];
        o[4] = (__bf16)b[0]; o[5] = (__bf16)b[1]; o[6] = (__bf16)b[2]; o[7] = (__bf16)b[3];
        *(bf16x8*)(xb + i) = o;
    } else {
        int idx = (bid - 6144) * 256 + threadIdx.x;   // [0, 73728)
        int n   = idx & 255;
        int t   = idx >> 8;          // [0, 288) = mat*96 + k8
        int mat = t / 96;
        int k8  = t - mat * 96;
        const float* W = (mat == 0) ? Wq : ((mat == 1) ? Wk : Wv);
        float scale = (mat == 0) ? qscale : 1.0f;
        bf16x8 o;
#pragma unroll
        for (int j = 0; j < 8; j++)
            o[j] = (__bf16)(W[(k8 * 8 + j) * HS_ + n] * scale);
        *(bf16x8*)&wt_all[((size_t)mat * HS_ + n) * C_ + k8 * 8] = o;
    }
}

// ---------------------------------------------------------------------------
// Kernel 2: fused QKV GEMM. BK=32, double-buffered LDS, one barrier/iter.
//   Q/K tiles: swapped operands (C rows carry d) -> coalesced bf16x4 stores.
// Fragment layouts (element index, all *8 = 8 bf16 per lane slot):
//   Q: ((((b*32+qt)*4 + w16)*8 + ks )*64 + lane)   lane&15 = q, quad = (d>>3)&3, j = d&7
//   K: ((((b*32+kt)*8 + ks )*4 + ns )*64 + lane)   lane&15 = s, quad = (d>>3)&3, j = d&7
//   V: ((((b*32+kt)*2 + ks2)*16 + ntv)*64 + lane)  lane&15 = d, quad = (s>>3)&3, j = s&7
// ---------------------------------------------------------------------------
__global__ __launch_bounds__(256) void proj_kernel(const __bf16* __restrict__ xb,
                                                   const __bf16* __restrict__ wt,
                                                   __bf16* __restrict__ qf_,
                                                   __bf16* __restrict__ kf_,
                                                   __bf16* __restrict__ vf_) {
    __shared__ alignas(16) __bf16 ldsA[2][128 * 32];   // 2 x 8 KB
    __shared__ alignas(16) __bf16 ldsB[2][128 * 32];   // 2 x 8 KB

    const int tid  = threadIdx.x;
    const int w    = tid >> 6;
    const int lane = tid & 63;
    const int cm   = lane & 15;
    const int quad = lane >> 4;
    const int wm   = w & 1;
    const int wn   = w >> 1;
    const int m0   = blockIdx.x * 128;
    const int n0   = blockIdx.y * 128;
    const int mat  = n0 >> 8;                 // 0=Q 1=K 2=V

    f32x4 acc[4][4];
#pragma unroll
    for (int i = 0; i < 4; i++)
#pragma unroll
        for (int j = 0; j < 4; j++) acc[i][j] = (f32x4){0.f, 0.f, 0.f, 0.f};

    // prologue: stage k-iter 0 into buffer 0
#pragma unroll
    for (int h = 0; h < 2; h++) {
        int c = tid + h * 256;   // 512 chunks: row = c>>2, col granule = (c&3)*8
        GLOAD_LDS16(xb + (size_t)(m0 + (c >> 2)) * C_ + (c & 3) * 8, &ldsA[0][c * 8]);
        GLOAD_LDS16(wt + (size_t)(n0 + (c >> 2)) * C_ + (c & 3) * 8, &ldsB[0][c * 8]);
    }

    for (int kt = 0; kt < 24; kt++) {
        const int cur = kt & 1;
        __syncthreads();   // drains vmcnt -> buf[cur] staged; prev reads done

        if (kt < 23) {
            const int k0 = (kt + 1) * 32;
#pragma unroll
            for (int h = 0; h < 2; h++) {
                int c = tid + h * 256;
                GLOAD_LDS16(xb + (size_t)(m0 + (c >> 2)) * C_ + k0 + (c & 3) * 8,
                            &ldsA[cur ^ 1][c * 8]);
                GLOAD_LDS16(wt + (size_t)(n0 + (c >> 2)) * C_ + k0 + (c & 3) * 8,
                            &ldsB[cur ^ 1][c * 8]);
            }
        }

        bf16x8 af[4], bfr[4];
#pragma unroll
        for (int mt = 0; mt < 4; mt++)
            af[mt] = *(const bf16x8*)&ldsA[cur][(wm * 64 + mt * 16 + cm) * 32 + quad * 8];
#pragma unroll
        for (int nt = 0; nt < 4; nt++)
            bfr[nt] = *(const bf16x8*)&ldsB[cur][(wn * 64 + nt * 16 + cm) * 32 + quad * 8];
        if (mat < 2) {
#pragma unroll
            for (int dt = 0; dt < 4; dt++)
#pragma unroll
                for (int qt2 = 0; qt2 < 4; qt2++)
                    acc[dt][qt2] = MFMA16(bfr[dt], af[qt2], acc[dt][qt2]);
        } else {
#pragma unroll
            for (int mt = 0; mt < 4; mt++)
#pragma unroll
                for (int nt = 0; nt < 4; nt++)
                    acc[mt][nt] = MFMA16(af[mt], bfr[nt], acc[mt][nt]);
        }
    }

    const int dBase = (n0 & 255) + wn * 64;
    const int b     = m0 >> 11;
    if (mat < 2) {
        const int rt2 = ((m0 & 2047) >> 6) + wm;   // 64-row tile within batch
        __bf16* dst = (mat == 0) ? qf_ : kf_;
#pragma unroll
        for (int dt = 0; dt < 4; dt++)
#pragma unroll
            for (int qt2 = 0; qt2 < 4; qt2++) {
                int d0    = dBase + dt * 16 + quad * 4;   // d of reg i = d0 + i
                int ksq   = d0 >> 5;
                int quadp = (d0 >> 3) & 3;
                int j0    = d0 & 7;
                size_t addr;
                if (mat == 0)
                    addr = ((((size_t)(b * 32 + rt2) * 4 + qt2) * 8 + ksq) * 64
                            + quadp * 16 + cm) * 8 + j0;
                else
                    addr = ((((size_t)(b * 32 + rt2) * 8 + ksq) * 4 + qt2) * 64
                            + quadp * 16 + cm) * 8 + j0;
                bf16x4 v4;
                v4[0] = (__bf16)acc[dt][qt2][0]; v4[1] = (__bf16)acc[dt][qt2][1];
                v4[2] = (__bf16)acc[dt][qt2][2]; v4[3] = (__bf16)acc[dt][qt2][3];
                *(bf16x4*)(dst + addr) = v4;
            }
    } else {
        const int rt = ((m0 & 2047) + wm * 64) >> 6;
#pragma unroll
        for (int mt = 0; mt < 4; mt++) {
            int ks2   = (mt >> 1) & 1;
            int quadF = (mt & 1) * 2 + (quad >> 1);
            int jb    = (quad & 1) * 4;
#pragma unroll
            for (int nt = 0; nt < 4; nt++) {
                int ntv = (dBase >> 4) + nt;
                size_t idx = ((((size_t)(b * 32 + rt) * 2 + ks2) * 16 + ntv) * 64
                              + quadF * 16 + cm) * 8 + jb;
                bf16x4 v4;
                v4[0] = (__bf16)acc[mt][nt][0]; v4[1] = (__bf16)acc[mt][nt][1];
                v4[2] = (__bf16)acc[mt][nt][2]; v4[3] = (__bf16)acc[mt][nt][3];
                *(bf16x4*)(vf_ + idx) = v4;
            }
        }
    }
}

// ---------------------------------------------------------------------------
// Kernel 3a: split-K causal flash partial — R11 body (32-key tiles, 36 KB
//   LDS -> 3 blocks/CU) + R12 chunking (512-key chunks -> half the Opart
//   traffic, 640 blocks). Fixed-anchor softmax, per-lane (q = cm), no
//   rescale; P private per wave (1 KB).
// ---------------------------------------------------------------------------
__global__ __launch_bounds__(256, 3) void flash_part(const __bf16* __restrict__ qf_,
                                                     const __bf16* __restrict__ kf_,
                                                     const __bf16* __restrict__ vf_,
                                                     __bf16* __restrict__ Opart,
                                                     float* __restrict__ mpart,
                                                     float* __restrict__ lpart) {
    __shared__ alignas(16) __bf16 ldsK[8 * 2 * 64 * 8];   // [ks8][ns2][lane]x8 = 16 KB
    __shared__ alignas(16) __bf16 ldsV[16 * 64 * 8];      // [ntv16][lane]x8  = 16 KB
    __shared__ alignas(16) __bf16 ldsP[4][512];           // per-wave P (1 KB)

    const int tid  = threadIdx.x;
    const int w    = tid >> 6;       // 0..3
    const int lane = tid & 63;
    const int cm   = lane & 15;      // = q column
    const int quad = lane >> 4;

    const int pid  = blockIdx.x;                // [0, 640)
    const int b    = pid & 7;                   // batch -> XCD spread
    const int r    = (CHUNKS_PER_BATCH - 1) - (pid >> 3);   // heavy chunks first
    int qb = 0, ci = 0;
    {
        int rr = r;
        for (int j = 0; j < 32; j++) {
            int c = (j >> 3) + 1;
            if (rr < c) { qb = j; ci = rr; break; }
            rr -= c;
        }
    }
    const int lpid = b * CHUNKS_PER_BATCH + r;  // output slot
    const int kt_begin = ci * 16;                       // 32-key tiles
    const int kt_end   = min(kt_begin + 16, 2 * qb + 2);

    // Q fragments (B-operand: lane&15 = q, quad*8+j = d), coalesced loads.
    const __bf16* qp = qf_ + (((size_t)(b * 32 + qb) * 4 + w) * 8) * 512 + lane * 8;
    bf16x8 qf[8];
#pragma unroll
    for (int ks = 0; ks < 8; ks++) qf[ks] = *(const bf16x8*)(qp + ks * 512);

    f32x4 accO[16];   // accO[nt][i]: d = nt*16 + quad*4 + i, q = cm
#pragma unroll
    for (int i = 0; i < 16; i++) accO[i] = (f32x4){0.f, 0.f, 0.f, 0.f};
    float mi = 0.f, li = 0.f;        // mi fixed after first tile

    const int wrow  = qb * 64 + w * 16;
    const int qglob = wrow + cm;

    for (int kt = kt_begin; kt < kt_end; kt++) {
        __syncthreads();   // (A) prior tile's LDS fully consumed

        // ---- stage K (16 KB) + V (16 KB) tile, async ----
        {
            const int kt64 = kt >> 1, kh = kt & 1;
            const __bf16* kgb = kf_ + (((size_t)(b * 32 + kt64) * 8) * 4 + kh * 2) * 512;
#pragma unroll
            for (int h = 0; h < 4; h++) {
                int g = h * 256 + tid;           // 16B slot id, 0..1023
                int ks = g >> 7, sub = g & 127;  // sub = ns2*64 + lane'
                GLOAD_LDS16(kgb + (size_t)ks * 4 * 512 + sub * 8,
                            ldsK + (h * 256 + w * 64) * 8);
            }
            const __bf16* vgb = vf_ + ((size_t)(b * 64 + kt) * 16) * 512;
#pragma unroll
            for (int h = 0; h < 4; h++) {
                int g = h * 256 + tid;           // ntv = g>>6, lane' = g&63
                GLOAD_LDS16(vgb + (size_t)g * 8,
                            ldsV + (h * 256 + w * 64) * 8);
            }
        }
        __syncthreads();   // (B) vmcnt drained -> K/V visible

        // ---- St = K Q^T  (32 s x 16 q per wave) ----
        f32x4 s[2];
#pragma unroll
        for (int i = 0; i < 2; i++) s[i] = (f32x4){0.f, 0.f, 0.f, 0.f};
#pragma unroll
        for (int ns = 0; ns < 2; ns++)
#pragma unroll
            for (int ks = 0; ks < 8; ks++) {
                bf16x8 kfr = *(const bf16x8*)&ldsK[(ks * 2 + ns) * 512 + lane * 8];
                s[ns] = MFMA16(kfr, qf[ks], s[ns]);
            }
        // ---- causal mask ----
        if (kt * 32 + 31 > wrow) {
#pragma unroll
            for (int ns = 0; ns < 2; ns++)
#pragma unroll
                for (int i = 0; i < 4; i++)
                    if (kt * 32 + ns * 16 + quad * 4 + i > qglob)
                        s[ns][i] = -__builtin_inff();
        }
        // ---- fixed-anchor softmax: establish m once (first tile) ----
        if (kt == kt_begin) {
            float pm = -__builtin_inff();
#pragma unroll
            for (int ns = 0; ns < 2; ns++)
#pragma unroll
                for (int i = 0; i < 4; i++) pm = fmaxf(pm, s[ns][i]);
            pm = fmaxf(pm, __shfl_xor(pm, 16));
            pm = fmaxf(pm, __shfl_xor(pm, 32));
            mi = pm;
        }
        float p[2][4], rs = 0.f;
#pragma unroll
        for (int ns = 0; ns < 2; ns++)
#pragma unroll
            for (int i = 0; i < 4; i++) {
                p[ns][i] = exp2f(s[ns][i] - mi);
                rs += p[ns][i];
            }
        rs += __shfl_xor(rs, 16);
        rs += __shfl_xor(rs, 32);
        li += rs;

        // ---- P -> private per-wave LDS in PV B-operand layout ----
#pragma unroll
        for (int ns = 0; ns < 2; ns++)
#pragma unroll
            for (int i2 = 0; i2 < 2; i2++) {
                bf16x2 d2;
                d2[0] = (__bf16)p[ns][2 * i2];
                d2[1] = (__bf16)p[ns][2 * i2 + 1];
                int off = ((ns * 2 + (quad >> 1)) * 16 + cm) * 8
                          + (quad & 1) * 4 + i2 * 2;
                *(bf16x2*)&ldsP[w][off] = d2;
            }
        // ---- O += V^T-frag x P-frag ----
        bf16x8 pfrag = *(const bf16x8*)&ldsP[w][(quad * 16 + cm) * 8];
#pragma unroll
        for (int nt = 0; nt < 16; nt++) {
            bf16x8 vfr = *(const bf16x8*)&ldsV[(nt * 64 + lane) * 8];
            accO[nt] = MFMA16(vfr, pfrag, accO[nt]);
        }
    }

    // ---- epilogue: coalesced bf16x4 stores + fp32 (m, l) ----
    __bf16* op = Opart + ((size_t)lpid * 64 + w * 16 + cm) * HS_;
#pragma unroll
    for (int nt = 0; nt < 16; nt++) {
        bf16x4 v4;
        v4[0] = (__bf16)accO[nt][0]; v4[1] = (__bf16)accO[nt][1];
        v4[2] = (__bf16)accO[nt][2]; v4[3] = (__bf16)accO[nt][3];
        *(bf16x4*)(op + nt * 16 + quad * 4) = v4;
    }
    if (quad == 0) {
        mpart[lpid * 64 + w * 16 + cm] = mi;
        lpart[lpid * 64 + w * 16 + cm] = li;
    }
}

// ---------------------------------------------------------------------------
// Kernel 3b: combine partials.  Grid (256, 4): block = (b, qb) x 16 rows.
// ---------------------------------------------------------------------------
__global__ __launch_bounds__(256) void flash_combine(const __bf16* __restrict__ Opart,
                                                     const float* __restrict__ mpart,
                                                     const float* __restrict__ lpart,
                                                     float* __restrict__ out) {
    const int b    = blockIdx.x >> 5;
    const int qb   = blockIdx.x & 31;
    const int nc   = (qb >> 3) + 1;
    const int pid0 = b * CHUNKS_PER_BATCH + chunk_cum64(qb);

    const int tid  = threadIdx.x;
    const int col  = (tid & 63) * 4;
    const int r0   = blockIdx.y * 16 + (tid >> 6) * 4;

    f32x4 ms = (f32x4){-__builtin_inff(), -__builtin_inff(),
                       -__builtin_inff(), -__builtin_inff()};
    for (int c = 0; c < nc; c++) {
        f32x4 m4 = *(const f32x4*)(mpart + (pid0 + c) * 64 + r0);
#pragma unroll
        for (int i = 0; i < 4; i++) ms[i] = fmaxf(ms[i], m4[i]);
    }
    f32x4 acc[4];
#pragma unroll
    for (int i = 0; i < 4; i++) acc[i] = (f32x4){0.f, 0.f, 0.f, 0.f};
    f32x4 lt = (f32x4){0.f, 0.f, 0.f, 0.f};
    for (int c = 0; c < nc; c++) {
        f32x4 m4 = *(const f32x4*)(mpart + (pid0 + c) * 64 + r0);
        f32x4 l4 = *(const f32x4*)(lpart + (pid0 + c) * 64 + r0);
#pragma unroll
        for (int i = 0; i < 4; i++) {
            float sc = exp2f(m4[i] - ms[i]);
            lt[i] += l4[i] * sc;
            bf16x4 o = *(const bf16x4*)(Opart
                        + ((size_t)(pid0 + c) * 64 + r0 + i) * HS_ + col);
            acc[i][0] += (float)o[0] * sc; acc[i][1] += (float)o[1] * sc;
            acc[i][2] += (float)o[2] * sc; acc[i][3] += (float)o[3] * sc;
        }
    }
#pragma unroll
    for (int i = 0; i < 4; i++) {
        float inv = 1.0f / lt[i];
        f32x4 res = (f32x4){acc[i][0] * inv, acc[i][1] * inv,
                            acc[i][2] * inv, acc[i][3] * inv};
        *(f32x4*)(out + ((size_t)(b * T_ + qb * 64 + r0 + i)) * HS_ + col) = res;
    }
}

// ---------------------------------------------------------------------------
extern "C" void kernel_launch(void* const* d_in, const int* in_sizes, int n_in,
                              void* d_out, int out_size, void* d_ws, size_t ws_size,
                              hipStream_t stream) {
    const float* x  = (const float*)d_in[0];
    const float* Wq = (const float*)d_in[1];
    const float* Wk = (const float*)d_in[2];
    const float* Wv = (const float*)d_in[3];
    float* out = (float*)d_out;

    char* ws = (char*)d_ws;
    size_t off = 0;
    __bf16* wt_all = (__bf16*)(ws + off); off += 1179648;
    __bf16* qfrag  = (__bf16*)(ws + off); off += 8388608;
    __bf16* kfrag  = (__bf16*)(ws + off); off += 8388608;
    __bf16* vfrag  = (__bf16*)(ws + off); off += 8388608;
    __bf16* xb     = (__bf16*)(ws + off);              // union with Opart
    __bf16* Opart  = (__bf16*)(ws + off); off += (size_t)NSLOT * 64 * HS_ * 2;
    float*  mpart  = (float*)(ws + off);  off += (size_t)NSLOT * 64 * 4;
    float*  lpart  = (float*)(ws + off);

    float qscale = 1.4426950408889634f / sqrtf((float)C_);

    prep_kernel<<<dim3(6432), 256, 0, stream>>>(x, Wq, Wk, Wv, xb, wt_all, qscale);
    proj_kernel<<<dim3(128, 6), 256, 0, stream>>>(xb, wt_all, qfrag, kfrag, vfrag);
    flash_part<<<dim3(NSLOT), 256, 0, stream>>>(qfrag, kfrag, vfrag, Opart, mpart, lpart);
    flash_combine<<<dim3(256, 4), 256, 0, stream>>>(Opart, mpart, lpart, out);
}